// Round 2
// baseline (4545.175 us; speedup 1.0000x reference)
//
#include <hip/hip_runtime.h>

#define BATCH 256
#define SEQ   128
#define EDIM  512
#define HDIM  1024
#define GDIM  4096   // 4*H
#define KCAT  1536   // E + H
#define PDIM  512
#define ODIM  6

typedef _Float16 f16;
typedef _Float16 f16x8 __attribute__((ext_vector_type(8)));
typedef float f32x4 __attribute__((ext_vector_type(4)));

// ---------------- workspace layout (bytes) ----------------
static const size_t XS_OFF    = 0;                                      // f16 [SEQ][BATCH][EDIM]
static const size_t WCAT_OFF  = XS_OFF    + (size_t)SEQ*BATCH*EDIM*2;   // f16 [GDIM][KCAT]
static const size_t WB_OFF    = WCAT_OFF  + (size_t)GDIM*KCAT*2;        // f16 [GDIM][EDIM]
static const size_t WPF_OFF   = WB_OFF    + (size_t)GDIM*EDIM*2;        // f16 [PDIM][2*HDIM]
static const size_t BIASF_OFF = WPF_OFF   + (size_t)PDIM*2*HDIM*2;      // f32 [GDIM]
static const size_t BIASB_OFF = BIASF_OFF + (size_t)GDIM*4;             // f32 [GDIM]
// ---- zeroed region start ----
static const size_t H0_OFF    = BIASB_OFF + (size_t)GDIM*4;             // f16 [BATCH][HDIM]
static const size_t H1_OFF    = H0_OFF    + (size_t)BATCH*HDIM*2;       // f16 [BATCH][HDIM]
static const size_t CB_OFF    = H1_OFF    + (size_t)BATCH*HDIM*2;       // f32 [BATCH][HDIM]
static const size_t CTR_OFF   = CB_OFF    + (size_t)BATCH*HDIM*4;       // u32 [4*32]
// ---- zeroed region end (CTR_OFF + 512) ----
static const size_t HCATF_OFF = CTR_OFF   + 512;                        // f16 [BATCH][2*HDIM]
static const size_t P_OFF     = HCATF_OFF + (size_t)BATCH*2*HDIM*2;     // f32 [BATCH][PDIM]

// ---------------- embedding gather + tanh -> f16 ----------------
__global__ __launch_bounds__(64) void embed_k(const int* __restrict__ seq,
                                              const float* __restrict__ emb,
                                              f16* __restrict__ xs) {
  int bid = blockIdx.x;                 // t*256 + b
  int t = bid >> 8, b = bid & 255;
  int tok = seq[b * SEQ + t];
  const float* src = emb + (size_t)tok * EDIM + threadIdx.x * 8;
  f16* dst = xs + (size_t)bid * EDIM + threadIdx.x * 8;
  float4 v0 = *(const float4*)src;
  float4 v1 = *(const float4*)(src + 4);
  f16x8 o;
  o[0] = (f16)tanhf(v0.x); o[1] = (f16)tanhf(v0.y);
  o[2] = (f16)tanhf(v0.z); o[3] = (f16)tanhf(v0.w);
  o[4] = (f16)tanhf(v1.x); o[5] = (f16)tanhf(v1.y);
  o[6] = (f16)tanhf(v1.z); o[7] = (f16)tanhf(v1.w);
  *(f16x8*)dst = o;
}

// ---------------- weight conversions ----------------
__global__ __launch_bounds__(256) void wcat_k(const float* __restrict__ wih,
                                              const float* __restrict__ whh,
                                              f16* __restrict__ wcat) {
  int idx = blockIdx.x * 256 + threadIdx.x;    // chunk of 8, KCAT/8 = 192 per row
  int n = idx / 192, c8 = (idx % 192) * 8;
  const float* src = (c8 < EDIM) ? (wih + (size_t)n * EDIM + c8)
                                 : (whh + (size_t)n * HDIM + (c8 - EDIM));
  float4 v0 = *(const float4*)src;
  float4 v1 = *(const float4*)(src + 4);
  f16x8 o;
  o[0] = (f16)v0.x; o[1] = (f16)v0.y; o[2] = (f16)v0.z; o[3] = (f16)v0.w;
  o[4] = (f16)v1.x; o[5] = (f16)v1.y; o[6] = (f16)v1.z; o[7] = (f16)v1.w;
  *(f16x8*)(wcat + (size_t)n * KCAT + c8) = o;
}

__global__ __launch_bounds__(256) void wb_k(const float* __restrict__ wih,
                                            f16* __restrict__ wb) {
  int idx = blockIdx.x * 256 + threadIdx.x;    // EDIM/8 = 64 chunks per row
  int n = idx >> 6, c8 = (idx & 63) * 8;
  const float* src = wih + (size_t)n * EDIM + c8;
  float4 v0 = *(const float4*)src;
  float4 v1 = *(const float4*)(src + 4);
  f16x8 o;
  o[0] = (f16)v0.x; o[1] = (f16)v0.y; o[2] = (f16)v0.z; o[3] = (f16)v0.w;
  o[4] = (f16)v1.x; o[5] = (f16)v1.y; o[6] = (f16)v1.z; o[7] = (f16)v1.w;
  *(f16x8*)(wb + (size_t)n * EDIM + c8) = o;
}

// generic f32 -> f16, 8 elems/thread
__global__ __launch_bounds__(256) void cvt8_k(const float* __restrict__ src,
                                              f16* __restrict__ dst) {
  int idx = blockIdx.x * 256 + threadIdx.x;
  const float* s = src + (size_t)idx * 8;
  float4 v0 = *(const float4*)s;
  float4 v1 = *(const float4*)(s + 4);
  f16x8 o;
  o[0] = (f16)v0.x; o[1] = (f16)v0.y; o[2] = (f16)v0.z; o[3] = (f16)v0.w;
  o[4] = (f16)v1.x; o[5] = (f16)v1.y; o[6] = (f16)v1.z; o[7] = (f16)v1.w;
  *(f16x8*)(dst + (size_t)idx * 8) = o;
}

__global__ __launch_bounds__(256) void bias_k(const float* __restrict__ bih_f,
                                              const float* __restrict__ bhh_f,
                                              const float* __restrict__ bih_b,
                                              const float* __restrict__ bhh_b,
                                              float* __restrict__ biasf,
                                              float* __restrict__ biasb) {
  int i = blockIdx.x * 256 + threadIdx.x;
  if (i < GDIM) biasf[i] = bih_f[i] + bhh_f[i];
  else { int k = i - GDIM; biasb[k] = bih_b[k] + bhh_b[k]; }
}

// ---------------- one-shot LSTM step (backward cell, h0=c0=0) ----------------
// Same proven structure as round 1; writes h as f16 with stride ldh.
__global__ __launch_bounds__(256) void lstm_step(
    const f16* __restrict__ A1, const f16* __restrict__ A2,
    int ld2, int K1, int Ktot,
    const f16* __restrict__ W, int ldw,
    const float* __restrict__ bias,
    const float* cin, float* cout,
    f16* __restrict__ hf16, int ldh)
{
  __shared__ __align__(16) f16 lsA[64 * 136];
  __shared__ __align__(16) f16 lsB[64 * 136];
  __shared__ float lsG[64 * 65];

  int tid = threadIdx.x;
  int m0 = blockIdx.x * 64;
  int j0 = blockIdx.y * 16;
  int w = tid >> 6, lane = tid & 63;
  int wm = (w >> 1) * 32, wn = (w & 1) * 32;
  int l15 = lane & 15, l4 = lane >> 4;

  f32x4 acc[2][2] = {};
  int nk = Ktot >> 7;

  for (int kt = 0; kt < nk; ++kt) {
    int k0 = kt << 7;
    #pragma unroll
    for (int cc = 0; cc < 4; ++cc) {
      int idx = tid + cc * 256;
      int row = idx >> 4, c8 = (idx & 15) << 3;
      int k = k0 + c8;
      const f16* sa = (k < K1) ? (A1 + (size_t)(m0 + row) * EDIM + k)
                               : (A2 + (size_t)(m0 + row) * ld2 + (k - K1));
      *(f16x8*)&lsA[row * 136 + c8] = *(const f16x8*)sa;
      int ng = ((row >> 4) << 10) + j0 + (row & 15);
      *(f16x8*)&lsB[row * 136 + c8] = *(const f16x8*)(W + (size_t)ng * ldw + k);
    }
    __syncthreads();
    #pragma unroll
    for (int ks = 0; ks < 4; ++ks) {
      int ko = ks * 32 + l4 * 8;
      f16x8 a0 = *(const f16x8*)&lsA[(wm + l15) * 136 + ko];
      f16x8 a1 = *(const f16x8*)&lsA[(wm + 16 + l15) * 136 + ko];
      f16x8 b0 = *(const f16x8*)&lsB[(wn + l15) * 136 + ko];
      f16x8 b1 = *(const f16x8*)&lsB[(wn + 16 + l15) * 136 + ko];
      acc[0][0] = __builtin_amdgcn_mfma_f32_16x16x32_f16(a0, b0, acc[0][0], 0, 0, 0);
      acc[0][1] = __builtin_amdgcn_mfma_f32_16x16x32_f16(a0, b1, acc[0][1], 0, 0, 0);
      acc[1][0] = __builtin_amdgcn_mfma_f32_16x16x32_f16(a1, b0, acc[1][0], 0, 0, 0);
      acc[1][1] = __builtin_amdgcn_mfma_f32_16x16x32_f16(a1, b1, acc[1][1], 0, 0, 0);
    }
    __syncthreads();
  }

  #pragma unroll
  for (int mi = 0; mi < 2; ++mi)
    #pragma unroll
    for (int ni = 0; ni < 2; ++ni) {
      int col = wn + ni * 16 + l15;
      int mr = wm + mi * 16 + l4 * 4;
      #pragma unroll
      for (int r = 0; r < 4; ++r)
        lsG[(mr + r) * 65 + col] = acc[mi][ni][r];
    }
  __syncthreads();

  int jl = tid & 15, mb = tid >> 4;
  int j = j0 + jl;
  #pragma unroll
  for (int mm = 0; mm < 4; ++mm) {
    int ml = mb + mm * 16;
    int m = m0 + ml;
    float gi = lsG[ml * 65 +      jl] + bias[j];
    float gf = lsG[ml * 65 + 16 + jl] + bias[HDIM + j];
    float gg = lsG[ml * 65 + 32 + jl] + bias[2 * HDIM + j];
    float go = lsG[ml * 65 + 48 + jl] + bias[3 * HDIM + j];
    float si = 1.f / (1.f + __expf(-gi));
    float sf = 1.f / (1.f + __expf(-gf));
    float so = 1.f / (1.f + __expf(-go));
    float c  = sf * cin[m * HDIM + j] + si * tanhf(gg);
    cout[m * HDIM + j] = c;
    float h = so * tanhf(c);
    hf16[(size_t)m * ldh + j] = (f16)h;
  }
}

// ---------------- persistent forward scan ----------------
// 256 WGs (cooperative), 1/CU. WG: chain = wg>>6 (m0 = chain*64), j0 = (wg&63)*16.
// Wave w holds W B-fragments for all 4 gates, K-slices kf = w + 4i (i<12), in VGPRs.
// A-fragments loaded straight from global (xs / h ping-pong). Cross-wave K-partial
// reduction fused with the LSTM pointwise through LDS. c lives in registers.
// Chain-local barrier: device-scope atomic counter + agent fences.
__global__ __launch_bounds__(256, 1) void lstm_persist(
    const f16* __restrict__ xs, const f16* __restrict__ W,
    const float* __restrict__ bias,
    f16* h0, f16* h1, f16* __restrict__ hcat,
    unsigned int* __restrict__ ctr)
{
  __shared__ float lsR[4][64][69];
  int tid = threadIdx.x;
  int wg = blockIdx.x;
  int chain = wg >> 6;
  int m0 = chain << 6;
  int j0 = (wg & 63) << 4;
  int w = tid >> 6, lane = tid & 63;
  int l15 = lane & 15, l4 = lane >> 4;

  // --- weight-stationary B fragments: Wf[gate][i], kf = w + 4*i ---
  f16x8 Wf[4][12];
  #pragma unroll
  for (int g = 0; g < 4; ++g)
    #pragma unroll
    for (int i = 0; i < 12; ++i) {
      int kf = w + 4 * i;
      Wf[g][i] = *(const f16x8*)(W + (size_t)((g << 10) + j0 + l15) * KCAT + kf * 32 + l4 * 8);
    }

  int kb = w * 32 + l4 * 8;                   // k base for i=0 (and h base for i=4)
  size_t offX[4], offH[4];
  #pragma unroll
  for (int ms = 0; ms < 4; ++ms) {
    int row = m0 + ms * 16 + l15;
    offX[ms] = (size_t)row * EDIM + kb;
    offH[ms] = (size_t)row * HDIM + kb;
  }

  int jl = tid & 15, mb = tid >> 4;
  float creg[4] = {0.f, 0.f, 0.f, 0.f};
  unsigned int* mctr = ctr + chain * 32;      // 128 B apart per chain

  for (int t = 0; t < SEQ; ++t) {
    const f16* xt = xs + (size_t)t * BATCH * EDIM;
    const f16* hp = (t & 1) ? h1 : h0;
    f16* hn = (t & 1) ? h0 : h1;

    f32x4 acc[4][4] = {};                      // [gate][m-sub]
    f16x8 afc[4], afn[4];
    #pragma unroll
    for (int ms = 0; ms < 4; ++ms) afc[ms] = *(const f16x8*)(xt + offX[ms]);
    #pragma unroll
    for (int i = 0; i < 12; ++i) {
      if (i < 11) {
        #pragma unroll
        for (int ms = 0; ms < 4; ++ms)
          afn[ms] = (i < 3) ? *(const f16x8*)(xt + offX[ms] + (size_t)(i + 1) * 128)
                            : *(const f16x8*)(hp + offH[ms] + (size_t)(i - 3) * 128);
      }
      #pragma unroll
      for (int g = 0; g < 4; ++g)
        #pragma unroll
        for (int ms = 0; ms < 4; ++ms)
          acc[g][ms] = __builtin_amdgcn_mfma_f32_16x16x32_f16(afc[ms], Wf[g][i], acc[g][ms], 0, 0, 0);
      #pragma unroll
      for (int ms = 0; ms < 4; ++ms) afc[ms] = afn[ms];
    }

    // cross-wave K reduction + pointwise (C/D: row = l4*4+r, col = l15)
    #pragma unroll
    for (int g = 0; g < 4; ++g)
      #pragma unroll
      for (int ms = 0; ms < 4; ++ms)
        #pragma unroll
        for (int r = 0; r < 4; ++r)
          lsR[w][ms * 16 + l4 * 4 + r][g * 16 + l15] = acc[g][ms][r];
    __syncthreads();

    #pragma unroll
    for (int mm = 0; mm < 4; ++mm) {
      int m = mb + mm * 16;
      float ga[4];
      #pragma unroll
      for (int g = 0; g < 4; ++g)
        ga[g] = lsR[0][m][g * 16 + jl] + lsR[1][m][g * 16 + jl]
              + lsR[2][m][g * 16 + jl] + lsR[3][m][g * 16 + jl]
              + bias[(g << 10) + j0 + jl];
      float si = 1.f / (1.f + __expf(-ga[0]));
      float sf = 1.f / (1.f + __expf(-ga[1]));
      float so = 1.f / (1.f + __expf(-ga[3]));
      float c = sf * creg[mm] + si * tanhf(ga[2]);
      creg[mm] = c;
      float h = so * tanhf(c);
      hn[(size_t)(m0 + m) * HDIM + j0 + jl] = (f16)h;
      if (t == SEQ - 1) hcat[(size_t)(m0 + m) * (2 * HDIM) + j0 + jl] = (f16)h;
    }

    if (t < SEQ - 1) {
      // release h stores, arrive, wait for the chain's 64 WGs, acquire
      __builtin_amdgcn_fence(__ATOMIC_RELEASE, "agent");
      __syncthreads();
      if (tid == 0) {
        __hip_atomic_fetch_add(mctr, 1u, __ATOMIC_RELAXED, __HIP_MEMORY_SCOPE_AGENT);
        unsigned int tgt = 64u * (unsigned)(t + 1);
        while (__hip_atomic_load(mctr, __ATOMIC_RELAXED, __HIP_MEMORY_SCOPE_AGENT) < tgt)
          __builtin_amdgcn_s_sleep(1);
      }
      __syncthreads();
      __builtin_amdgcn_fence(__ATOMIC_ACQUIRE, "agent");
    }
  }
}

// ---------------- p = hcat @ Wp^T + bp via MFMA (f16 in, f32 out) ----------------
__global__ __launch_bounds__(256) void gemmp_k(const f16* __restrict__ A,
                                               const f16* __restrict__ B,
                                               const float* __restrict__ bias,
                                               float* __restrict__ out) {
  __shared__ __align__(16) f16 lsA[64 * 136];
  __shared__ __align__(16) f16 lsB[64 * 136];
  int tid = threadIdx.x;
  int m0 = blockIdx.x * 64, n0 = blockIdx.y * 64;
  int w = tid >> 6, lane = tid & 63;
  int wm = (w >> 1) * 32, wn = (w & 1) * 32;
  int l15 = lane & 15, l4 = lane >> 4;
  f32x4 acc[2][2] = {};
  for (int kt = 0; kt < 16; ++kt) {            // K = 2048
    int k0 = kt << 7;
    #pragma unroll
    for (int cc = 0; cc < 4; ++cc) {
      int idx = tid + cc * 256;
      int row = idx >> 4, c8 = (idx & 15) << 3;
      *(f16x8*)&lsA[row * 136 + c8] = *(const f16x8*)(A + (size_t)(m0 + row) * (2 * HDIM) + k0 + c8);
      *(f16x8*)&lsB[row * 136 + c8] = *(const f16x8*)(B + (size_t)(n0 + row) * (2 * HDIM) + k0 + c8);
    }
    __syncthreads();
    #pragma unroll
    for (int ks = 0; ks < 4; ++ks) {
      int ko = ks * 32 + l4 * 8;
      f16x8 a0 = *(const f16x8*)&lsA[(wm + l15) * 136 + ko];
      f16x8 a1 = *(const f16x8*)&lsA[(wm + 16 + l15) * 136 + ko];
      f16x8 b0 = *(const f16x8*)&lsB[(wn + l15) * 136 + ko];
      f16x8 b1 = *(const f16x8*)&lsB[(wn + 16 + l15) * 136 + ko];
      acc[0][0] = __builtin_amdgcn_mfma_f32_16x16x32_f16(a0, b0, acc[0][0], 0, 0, 0);
      acc[0][1] = __builtin_amdgcn_mfma_f32_16x16x32_f16(a0, b1, acc[0][1], 0, 0, 0);
      acc[1][0] = __builtin_amdgcn_mfma_f32_16x16x32_f16(a1, b0, acc[1][0], 0, 0, 0);
      acc[1][1] = __builtin_amdgcn_mfma_f32_16x16x32_f16(a1, b1, acc[1][1], 0, 0, 0);
    }
    __syncthreads();
  }
  #pragma unroll
  for (int mi = 0; mi < 2; ++mi)
    #pragma unroll
    for (int ni = 0; ni < 2; ++ni)
      #pragma unroll
      for (int r = 0; r < 4; ++r) {
        int m = m0 + wm + mi * 16 + l4 * 4 + r;
        int n = n0 + wn + ni * 16 + l15;
        out[(size_t)m * PDIM + n] = acc[mi][ni][r] + bias[n];
      }
}

// ---------------- out = sigmoid(p @ Wc^T + bc) ----------------
__global__ __launch_bounds__(64) void proj2_k(const float* __restrict__ p,
                                              const float* __restrict__ Wc,
                                              const float* __restrict__ bc,
                                              float* __restrict__ out) {
  int m = blockIdx.x, l = threadIdx.x;
  float pv[8];
  #pragma unroll
  for (int q = 0; q < 8; ++q) pv[q] = p[(size_t)m * PDIM + l + 64 * q];
  #pragma unroll
  for (int c = 0; c < ODIM; ++c) {
    float s = 0.f;
    #pragma unroll
    for (int q = 0; q < 8; ++q) s += pv[q] * Wc[c * PDIM + l + 64 * q];
    #pragma unroll
    for (int off = 32; off > 0; off >>= 1) s += __shfl_down(s, off);
    if (l == 0) out[m * ODIM + c] = 1.f / (1.f + __expf(-(s + bc[c])));
  }
}

extern "C" void kernel_launch(void* const* d_in, const int* in_sizes, int n_in,
                              void* d_out, int out_size, void* d_ws, size_t ws_size,
                              hipStream_t stream) {
  const int*   seq   = (const int*)d_in[0];
  const float* emb   = (const float*)d_in[1];
  const float* wih_f = (const float*)d_in[2];
  const float* whh_f = (const float*)d_in[3];
  const float* bih_f = (const float*)d_in[4];
  const float* bhh_f = (const float*)d_in[5];
  const float* wih_b = (const float*)d_in[6];
  const float* bih_b = (const float*)d_in[8];
  const float* bhh_b = (const float*)d_in[9];
  const float* Wp    = (const float*)d_in[10];
  const float* bp    = (const float*)d_in[11];
  const float* Wc    = (const float*)d_in[12];
  const float* bc    = (const float*)d_in[13];

  char* ws = (char*)d_ws;
  f16*   xs    = (f16*)(ws + XS_OFF);
  f16*   wcat  = (f16*)(ws + WCAT_OFF);
  f16*   wb    = (f16*)(ws + WB_OFF);
  f16*   wpf   = (f16*)(ws + WPF_OFF);
  float* biasf = (float*)(ws + BIASF_OFF);
  float* biasb = (float*)(ws + BIASB_OFF);
  f16*   h0    = (f16*)(ws + H0_OFF);
  f16*   h1    = (f16*)(ws + H1_OFF);
  float* cb    = (float*)(ws + CB_OFF);
  unsigned int* ctr = (unsigned int*)(ws + CTR_OFF);
  f16*   hcatf = (f16*)(ws + HCATF_OFF);
  float* p     = (float*)(ws + P_OFF);

  // zero h0, h1, cb, ctr (contiguous)
  hipMemsetAsync(ws + H0_OFF, 0, (CTR_OFF + 512) - H0_OFF, stream);

  wcat_k<<<(GDIM * KCAT / 8) / 256, 256, 0, stream>>>(wih_f, whh_f, wcat);
  wb_k<<<(GDIM * EDIM / 8) / 256, 256, 0, stream>>>(wih_b, wb);
  cvt8_k<<<(PDIM * 2 * HDIM / 8) / 256, 256, 0, stream>>>(Wp, wpf);
  bias_k<<<(2 * GDIM) / 256, 256, 0, stream>>>(bih_f, bhh_f, bih_b, bhh_b, biasf, biasb);
  embed_k<<<SEQ * BATCH, 64, 0, stream>>>(seq, emb, xs);

  // backward cell collapses to ONE step on xs[0] with zero state; h -> hcat cols [H, 2H)
  lstm_step<<<dim3(4, 64), 256, 0, stream>>>(xs, xs, EDIM, EDIM, EDIM,
      wb, EDIM, biasb, cb, cb, hcatf + HDIM, 2 * HDIM);

  // forward scan: one persistent cooperative kernel, 128 steps
  {
    void* kargs[] = { (void*)&xs, (void*)&wcat, (void*)&biasf, (void*)&h0,
                      (void*)&h1, (void*)&hcatf, (void*)&ctr };
    hipLaunchCooperativeKernel((const void*)lstm_persist, dim3(256), dim3(256),
                               kargs, 0, stream);
  }

  gemmp_k<<<dim3(4, 8), 256, 0, stream>>>(hcatf, wpf, bp, p);
  proj2_k<<<BATCH, 64, 0, stream>>>(p, Wc, bc, (float*)d_out);
}

// Round 4
// 1981.316 us; speedup vs baseline: 2.2940x; 2.2940x over previous
//
#include <hip/hip_runtime.h>

#define BATCH 256
#define SEQ   128
#define EDIM  512
#define HDIM  1024
#define GDIM  4096   // 4*H
#define KCAT  1536   // E + H
#define PDIM  512
#define ODIM  6

typedef _Float16 f16;
typedef _Float16 f16x8 __attribute__((ext_vector_type(8)));
typedef float f32x4 __attribute__((ext_vector_type(4)));

// ---------------- workspace layout (bytes) ----------------
static const size_t XS_OFF    = 0;                                      // f16 [SEQ][BATCH][EDIM]
static const size_t WCAT_OFF  = XS_OFF    + (size_t)SEQ*BATCH*EDIM*2;   // f16 [GDIM][KCAT]
static const size_t WB_OFF    = WCAT_OFF  + (size_t)GDIM*KCAT*2;        // f16 [GDIM][EDIM]
static const size_t WPF_OFF   = WB_OFF    + (size_t)GDIM*EDIM*2;        // f16 [PDIM][2*HDIM]
static const size_t BIASF_OFF = WPF_OFF   + (size_t)PDIM*2*HDIM*2;      // f32 [GDIM]
static const size_t BIASB_OFF = BIASF_OFF + (size_t)GDIM*4;             // f32 [GDIM]
// ---- zeroed region start ----
static const size_t H0_OFF    = BIASB_OFF + (size_t)GDIM*4;             // f16 [BATCH][HDIM]
static const size_t H1_OFF    = H0_OFF    + (size_t)BATCH*HDIM*2;       // f16 [BATCH][HDIM]
static const size_t CB_OFF    = H1_OFF    + (size_t)BATCH*HDIM*2;       // f32 [BATCH][HDIM]
static const size_t CTR_OFF   = CB_OFF    + (size_t)BATCH*HDIM*4;       // u32 [4*32]
// ---- zeroed region end (CTR_OFF + 512) ----
static const size_t HCATF_OFF = CTR_OFF   + 512;                        // f16 [BATCH][2*HDIM]
static const size_t P_OFF     = HCATF_OFF + (size_t)BATCH*2*HDIM*2;     // f32 [BATCH][PDIM]

// ---------------- embedding gather + tanh -> f16 (proven r1/r2 form) --------
__global__ __launch_bounds__(64) void embed_k(const int* __restrict__ seq,
                                              const float* __restrict__ emb,
                                              f16* __restrict__ xs) {
  int bid = blockIdx.x;                 // t*256 + b
  int t = bid >> 8, b = bid & 255;
  int tok = seq[b * SEQ + t];
  const float* src = emb + (size_t)tok * EDIM + threadIdx.x * 8;
  f16* dst = xs + (size_t)bid * EDIM + threadIdx.x * 8;
  float4 v0 = *(const float4*)src;
  float4 v1 = *(const float4*)(src + 4);
  f16x8 o;
  o[0] = (f16)tanhf(v0.x); o[1] = (f16)tanhf(v0.y);
  o[2] = (f16)tanhf(v0.z); o[3] = (f16)tanhf(v0.w);
  o[4] = (f16)tanhf(v1.x); o[5] = (f16)tanhf(v1.y);
  o[6] = (f16)tanhf(v1.z); o[7] = (f16)tanhf(v1.w);
  *(f16x8*)dst = o;
}

// ---------------- weight conversions ----------------
__global__ __launch_bounds__(256) void wcat_k(const float* __restrict__ wih,
                                              const float* __restrict__ whh,
                                              f16* __restrict__ wcat) {
  int idx = blockIdx.x * 256 + threadIdx.x;    // chunk of 8, KCAT/8 = 192 per row
  int n = idx / 192, c8 = (idx % 192) * 8;
  const float* src = (c8 < EDIM) ? (wih + (size_t)n * EDIM + c8)
                                 : (whh + (size_t)n * HDIM + (c8 - EDIM));
  float4 v0 = *(const float4*)src;
  float4 v1 = *(const float4*)(src + 4);
  f16x8 o;
  o[0] = (f16)v0.x; o[1] = (f16)v0.y; o[2] = (f16)v0.z; o[3] = (f16)v0.w;
  o[4] = (f16)v1.x; o[5] = (f16)v1.y; o[6] = (f16)v1.z; o[7] = (f16)v1.w;
  *(f16x8*)(wcat + (size_t)n * KCAT + c8) = o;
}

__global__ __launch_bounds__(256) void wb_k(const float* __restrict__ wih,
                                            f16* __restrict__ wb) {
  int idx = blockIdx.x * 256 + threadIdx.x;    // EDIM/8 = 64 chunks per row
  int n = idx >> 6, c8 = (idx & 63) * 8;
  const float* src = wih + (size_t)n * EDIM + c8;
  float4 v0 = *(const float4*)src;
  float4 v1 = *(const float4*)(src + 4);
  f16x8 o;
  o[0] = (f16)v0.x; o[1] = (f16)v0.y; o[2] = (f16)v0.z; o[3] = (f16)v0.w;
  o[4] = (f16)v1.x; o[5] = (f16)v1.y; o[6] = (f16)v1.z; o[7] = (f16)v1.w;
  *(f16x8*)(wb + (size_t)n * EDIM + c8) = o;
}

// generic f32 -> f16, 8 elems/thread
__global__ __launch_bounds__(256) void cvt8_k(const float* __restrict__ src,
                                              f16* __restrict__ dst) {
  int idx = blockIdx.x * 256 + threadIdx.x;
  const float* s = src + (size_t)idx * 8;
  float4 v0 = *(const float4*)s;
  float4 v1 = *(const float4*)(s + 4);
  f16x8 o;
  o[0] = (f16)v0.x; o[1] = (f16)v0.y; o[2] = (f16)v0.z; o[3] = (f16)v0.w;
  o[4] = (f16)v1.x; o[5] = (f16)v1.y; o[6] = (f16)v1.z; o[7] = (f16)v1.w;
  *(f16x8*)(dst + (size_t)idx * 8) = o;
}

__global__ __launch_bounds__(256) void bias_k(const float* __restrict__ bih_f,
                                              const float* __restrict__ bhh_f,
                                              const float* __restrict__ bih_b,
                                              const float* __restrict__ bhh_b,
                                              float* __restrict__ biasf,
                                              float* __restrict__ biasb) {
  int i = blockIdx.x * 256 + threadIdx.x;
  if (i < GDIM) biasf[i] = bih_f[i] + bhh_f[i];
  else { int k = i - GDIM; biasb[k] = bih_b[k] + bhh_b[k]; }
}

// ---------------- one-shot LSTM step (backward cell, h0=c0=0) ----------------
__global__ __launch_bounds__(256) void lstm_step(
    const f16* __restrict__ A1, const f16* __restrict__ A2,
    int ld2, int K1, int Ktot,
    const f16* __restrict__ W, int ldw,
    const float* __restrict__ bias,
    const float* cin, float* cout,
    f16* __restrict__ hf16, int ldh)
{
  __shared__ __align__(16) f16 lsA[64 * 136];
  __shared__ __align__(16) f16 lsB[64 * 136];
  __shared__ float lsG[64 * 65];

  int tid = threadIdx.x;
  int m0 = blockIdx.x * 64;
  int j0 = blockIdx.y * 16;
  int w = tid >> 6, lane = tid & 63;
  int wm = (w >> 1) * 32, wn = (w & 1) * 32;
  int l15 = lane & 15, l4 = lane >> 4;

  f32x4 acc[2][2] = {};
  int nk = Ktot >> 7;

  for (int kt = 0; kt < nk; ++kt) {
    int k0 = kt << 7;
    #pragma unroll
    for (int cc = 0; cc < 4; ++cc) {
      int idx = tid + cc * 256;
      int row = idx >> 4, c8 = (idx & 15) << 3;
      int k = k0 + c8;
      const f16* sa = (k < K1) ? (A1 + (size_t)(m0 + row) * EDIM + k)
                               : (A2 + (size_t)(m0 + row) * ld2 + (k - K1));
      *(f16x8*)&lsA[row * 136 + c8] = *(const f16x8*)sa;
      int ng = ((row >> 4) << 10) + j0 + (row & 15);
      *(f16x8*)&lsB[row * 136 + c8] = *(const f16x8*)(W + (size_t)ng * ldw + k);
    }
    __syncthreads();
    #pragma unroll
    for (int ks = 0; ks < 4; ++ks) {
      int ko = ks * 32 + l4 * 8;
      f16x8 a0 = *(const f16x8*)&lsA[(wm + l15) * 136 + ko];
      f16x8 a1 = *(const f16x8*)&lsA[(wm + 16 + l15) * 136 + ko];
      f16x8 b0 = *(const f16x8*)&lsB[(wn + l15) * 136 + ko];
      f16x8 b1 = *(const f16x8*)&lsB[(wn + 16 + l15) * 136 + ko];
      acc[0][0] = __builtin_amdgcn_mfma_f32_16x16x32_f16(a0, b0, acc[0][0], 0, 0, 0);
      acc[0][1] = __builtin_amdgcn_mfma_f32_16x16x32_f16(a0, b1, acc[0][1], 0, 0, 0);
      acc[1][0] = __builtin_amdgcn_mfma_f32_16x16x32_f16(a1, b0, acc[1][0], 0, 0, 0);
      acc[1][1] = __builtin_amdgcn_mfma_f32_16x16x32_f16(a1, b1, acc[1][1], 0, 0, 0);
    }
    __syncthreads();
  }

  #pragma unroll
  for (int mi = 0; mi < 2; ++mi)
    #pragma unroll
    for (int ni = 0; ni < 2; ++ni) {
      int col = wn + ni * 16 + l15;
      int mr = wm + mi * 16 + l4 * 4;
      #pragma unroll
      for (int r = 0; r < 4; ++r)
        lsG[(mr + r) * 65 + col] = acc[mi][ni][r];
    }
  __syncthreads();

  int jl = tid & 15, mb = tid >> 4;
  int j = j0 + jl;
  #pragma unroll
  for (int mm = 0; mm < 4; ++mm) {
    int ml = mb + mm * 16;
    int m = m0 + ml;
    float gi = lsG[ml * 65 +      jl] + bias[j];
    float gf = lsG[ml * 65 + 16 + jl] + bias[HDIM + j];
    float gg = lsG[ml * 65 + 32 + jl] + bias[2 * HDIM + j];
    float go = lsG[ml * 65 + 48 + jl] + bias[3 * HDIM + j];
    float si = 1.f / (1.f + __expf(-gi));
    float sf = 1.f / (1.f + __expf(-gf));
    float so = 1.f / (1.f + __expf(-go));
    float c  = sf * cin[m * HDIM + j] + si * tanhf(gg);
    cout[m * HDIM + j] = c;
    float h = so * tanhf(c);
    hf16[(size_t)m * ldh + j] = (f16)h;
  }
}

// device-coherent (sc1) h fragment load: 2 x relaxed agent-scope b64 atomics.
// Bypasses the non-coherent per-XCD L2; served by the memory-side IF$.
__device__ __forceinline__ f16x8 load_h_sc(const f16* p) {
  const unsigned long long* q = (const unsigned long long*)p;
  union { unsigned long long u[2]; f16x8 v; } r;
  r.u[0] = __hip_atomic_load(q,     __ATOMIC_RELAXED, __HIP_MEMORY_SCOPE_AGENT);
  r.u[1] = __hip_atomic_load(q + 1, __ATOMIC_RELAXED, __HIP_MEMORY_SCOPE_AGENT);
  return r.v;
}

// ---------------- persistent forward scan (fence-free) ----------------
// 256 WGs cooperative. chain = wg>>6 (m0 = chain*64), j0 = (wg&63)*16.
// Wave w covers K-slices kf = 2w + (i&1) + 8*(i>>1) (contiguous 64B per h-row
// per iter-pair -> full-sector coherent reads).
// h exchanged via sc1 (agent-scope relaxed atomic) stores/loads; barrier is
// vmcnt(0) + device atomic counter; NO cache-flushing fences. A data
// dependency (guard, always 0) blocks compiler hoisting past the spin.
// Spin has a watchdog: a protocol bug shows as wrong output, not a GPU hang.
__global__ __launch_bounds__(256, 1) void lstm_persist(
    const f16* __restrict__ xs, const f16* __restrict__ W,
    const float* __restrict__ bias,
    f16* h0, f16* h1, f16* __restrict__ hcat,
    unsigned int* __restrict__ ctr)
{
  __shared__ float lsR[4][64][69];
  __shared__ unsigned int sTok;
  int tid = threadIdx.x;
  int wg = blockIdx.x;
  int chain = wg >> 6;
  int m0 = chain << 6;
  int j0 = (wg & 63) << 4;
  int w = tid >> 6, lane = tid & 63;
  int l15 = lane & 15, l4 = lane >> 4;

  // --- W B-fragments: kf(i) = 2w + (i&1) + 8*(i>>1) ---
  f16x8 Wf[4][12];
  #pragma unroll
  for (int g = 0; g < 4; ++g)
    #pragma unroll
    for (int i = 0; i < 12; ++i) {
      int kf = 2 * w + (i & 1) + 8 * (i >> 1);
      Wf[g][i] = *(const f16x8*)(W + (size_t)((g << 10) + j0 + l15) * KCAT + kf * 32 + l4 * 8);
    }

  int kb = 64 * w + l4 * 8;               // wave-base k offset (elements)
  size_t offX[4], offH[4];
  #pragma unroll
  for (int ms = 0; ms < 4; ++ms) {
    int row = m0 + ms * 16 + l15;
    offX[ms] = (size_t)row * EDIM + kb;
    offH[ms] = (size_t)row * HDIM + kb;
  }

  int jl = tid & 15, mb = tid >> 4;
  float creg[4] = {0.f, 0.f, 0.f, 0.f};
  unsigned int* mctr = ctr + chain * 32;  // 128 B apart per chain
  size_t guard = 0;

  #pragma unroll 1
  for (int t = 0; t < SEQ; ++t) {
    const f16* xtg = xs + (size_t)t * BATCH * EDIM + guard;
    const f16* hpg = ((t & 1) ? h1 : h0) + guard;
    f16* hn = (t & 1) ? h0 : h1;

    // iter i covers k = 64w + 32*(i&1) + 256*(i>>1); i<4 -> x, i>=4 -> h
    f32x4 acc[4][4] = {};                 // [gate][m-sub]
    f16x8 pf[3][4];                       // depth-3 prefetch, statically indexed
    #pragma unroll
    for (int d = 0; d < 3; ++d)
      #pragma unroll
      for (int ms = 0; ms < 4; ++ms)
        pf[d][ms] = *(const f16x8*)(xtg + offX[ms] + (size_t)((d & 1) * 32 + (d >> 1) * 256));

    #pragma unroll
    for (int i = 0; i < 12; ++i) {
      f16x8 cur[4];
      #pragma unroll
      for (int ms = 0; ms < 4; ++ms) cur[ms] = pf[i % 3][ms];
      if (i + 3 < 12) {
        int ip = i + 3;
        size_t xoff = (size_t)((ip & 1) * 32 + (ip >> 1) * 256);
        size_t hoff = (size_t)((ip & 1) * 32 + ((ip >> 1) - 2) * 256);
        #pragma unroll
        for (int ms = 0; ms < 4; ++ms)
          pf[i % 3][ms] = (ip < 4) ? *(const f16x8*)(xtg + offX[ms] + xoff)
                                   : load_h_sc(hpg + offH[ms] + hoff);
      }
      #pragma unroll
      for (int g = 0; g < 4; ++g)
        #pragma unroll
        for (int ms = 0; ms < 4; ++ms)
          acc[g][ms] = __builtin_amdgcn_mfma_f32_16x16x32_f16(cur[ms], Wf[g][i], acc[g][ms], 0, 0, 0);
    }

    // cross-wave K reduction (C/D: row = l4*4+r, col = l15)
    #pragma unroll
    for (int g = 0; g < 4; ++g)
      #pragma unroll
      for (int ms = 0; ms < 4; ++ms)
        #pragma unroll
        for (int r = 0; r < 4; ++r)
          lsR[w][ms * 16 + l4 * 4 + r][g * 16 + l15] = acc[g][ms][r];
    __syncthreads();

    // pointwise; h stored packed b32 via sc1 atomic (lane-pair shfl)
    #pragma unroll
    for (int mm = 0; mm < 4; ++mm) {
      int ml = mb + mm * 16;
      int m = m0 + ml;
      float ga[4];
      #pragma unroll
      for (int g = 0; g < 4; ++g)
        ga[g] = lsR[0][ml][g * 16 + jl] + lsR[1][ml][g * 16 + jl]
              + lsR[2][ml][g * 16 + jl] + lsR[3][ml][g * 16 + jl]
              + bias[(g << 10) + j0 + jl];
      float si = 1.f / (1.f + __expf(-ga[0]));
      float sf = 1.f / (1.f + __expf(-ga[1]));
      float so = 1.f / (1.f + __expf(-ga[3]));
      float c = sf * creg[mm] + si * tanhf(ga[2]);
      creg[mm] = c;
      float h = so * tanhf(c);
      float hx = __shfl_xor(h, 1);
      if ((jl & 1) == 0) {
        union { f16 h2[2]; unsigned int u; } pk;
        pk.h2[0] = (f16)h; pk.h2[1] = (f16)hx;
        __hip_atomic_store((unsigned int*)(hn + (size_t)m * HDIM + j0 + jl), pk.u,
                           __ATOMIC_RELAXED, __HIP_MEMORY_SCOPE_AGENT);
      }
      if (t == SEQ - 1) hcat[(size_t)m * (2 * HDIM) + j0 + jl] = (f16)h;
    }

    if (t < SEQ - 1) {
      // drain this wave's sc1 stores to the coherence point, then arrive+wait
      asm volatile("s_waitcnt vmcnt(0)" ::: "memory");
      __syncthreads();
      if (tid == 0) {
        __hip_atomic_fetch_add(mctr, 1u, __ATOMIC_RELAXED, __HIP_MEMORY_SCOPE_AGENT);
        unsigned int tgt = 64u * (unsigned int)(t + 1);
        unsigned int obs = __hip_atomic_load(mctr, __ATOMIC_RELAXED, __HIP_MEMORY_SCOPE_AGENT);
        unsigned int spins = 0;
        while (obs < tgt && spins < (1u << 20)) {   // watchdog: fail visibly, never hang
          __builtin_amdgcn_s_sleep(1);
          obs = __hip_atomic_load(mctr, __ATOMIC_RELAXED, __HIP_MEMORY_SCOPE_AGENT);
          ++spins;
        }
        sTok = obs;
      }
      __syncthreads();
      guard = (size_t)(sTok >> 31);      // always 0; forces dependency order
    }
  }
}

// ---------------- p = hcat @ Wp^T + bp via MFMA (f16 in, f32 out) ----------------
__global__ __launch_bounds__(256) void gemmp_k(const f16* __restrict__ A,
                                               const f16* __restrict__ B,
                                               const float* __restrict__ bias,
                                               float* __restrict__ out) {
  __shared__ __align__(16) f16 lsA[64 * 136];
  __shared__ __align__(16) f16 lsB[64 * 136];
  int tid = threadIdx.x;
  int m0 = blockIdx.x * 64, n0 = blockIdx.y * 64;
  int w = tid >> 6, lane = tid & 63;
  int wm = (w >> 1) * 32, wn = (w & 1) * 32;
  int l15 = lane & 15, l4 = lane >> 4;
  f32x4 acc[2][2] = {};
  for (int kt = 0; kt < 16; ++kt) {            // K = 2048
    int k0 = kt << 7;
    #pragma unroll
    for (int cc = 0; cc < 4; ++cc) {
      int idx = tid + cc * 256;
      int row = idx >> 4, c8 = (idx & 15) << 3;
      *(f16x8*)&lsA[row * 136 + c8] = *(const f16x8*)(A + (size_t)(m0 + row) * (2 * HDIM) + k0 + c8);
      *(f16x8*)&lsB[row * 136 + c8] = *(const f16x8*)(B + (size_t)(n0 + row) * (2 * HDIM) + k0 + c8);
    }
    __syncthreads();
    #pragma unroll
    for (int ks = 0; ks < 4; ++ks) {
      int ko = ks * 32 + l4 * 8;
      f16x8 a0 = *(const f16x8*)&lsA[(wm + l15) * 136 + ko];
      f16x8 a1 = *(const f16x8*)&lsA[(wm + 16 + l15) * 136 + ko];
      f16x8 b0 = *(const f16x8*)&lsB[(wn + l15) * 136 + ko];
      f16x8 b1 = *(const f16x8*)&lsB[(wn + 16 + l15) * 136 + ko];
      acc[0][0] = __builtin_amdgcn_mfma_f32_16x16x32_f16(a0, b0, acc[0][0], 0, 0, 0);
      acc[0][1] = __builtin_amdgcn_mfma_f32_16x16x32_f16(a0, b1, acc[0][1], 0, 0, 0);
      acc[1][0] = __builtin_amdgcn_mfma_f32_16x16x32_f16(a1, b0, acc[1][0], 0, 0, 0);
      acc[1][1] = __builtin_amdgcn_mfma_f32_16x16x32_f16(a1, b1, acc[1][1], 0, 0, 0);
    }
    __syncthreads();
  }
  #pragma unroll
  for (int mi = 0; mi < 2; ++mi)
    #pragma unroll
    for (int ni = 0; ni < 2; ++ni)
      #pragma unroll
      for (int r = 0; r < 4; ++r) {
        int m = m0 + wm + mi * 16 + l4 * 4 + r;
        int n = n0 + wn + ni * 16 + l15;
        out[(size_t)m * PDIM + n] = acc[mi][ni][r] + bias[n];
      }
}

// ---------------- out = sigmoid(p @ Wc^T + bc) ----------------
__global__ __launch_bounds__(64) void proj2_k(const float* __restrict__ p,
                                              const float* __restrict__ Wc,
                                              const float* __restrict__ bc,
                                              float* __restrict__ out) {
  int m = blockIdx.x, l = threadIdx.x;
  float pv[8];
  #pragma unroll
  for (int q = 0; q < 8; ++q) pv[q] = p[(size_t)m * PDIM + l + 64 * q];
  #pragma unroll
  for (int c = 0; c < ODIM; ++c) {
    float s = 0.f;
    #pragma unroll
    for (int q = 0; q < 8; ++q) s += pv[q] * Wc[c * PDIM + l + 64 * q];
    #pragma unroll
    for (int off = 32; off > 0; off >>= 1) s += __shfl_down(s, off);
    if (l == 0) out[m * ODIM + c] = 1.f / (1.f + __expf(-(s + bc[c])));
  }
}

extern "C" void kernel_launch(void* const* d_in, const int* in_sizes, int n_in,
                              void* d_out, int out_size, void* d_ws, size_t ws_size,
                              hipStream_t stream) {
  const int*   seq   = (const int*)d_in[0];
  const float* emb   = (const float*)d_in[1];
  const float* wih_f = (const float*)d_in[2];
  const float* whh_f = (const float*)d_in[3];
  const float* bih_f = (const float*)d_in[4];
  const float* bhh_f = (const float*)d_in[5];
  const float* wih_b = (const float*)d_in[6];
  const float* bih_b = (const float*)d_in[8];
  const float* bhh_b = (const float*)d_in[9];
  const float* Wp    = (const float*)d_in[10];
  const float* bp    = (const float*)d_in[11];
  const float* Wc    = (const float*)d_in[12];
  const float* bc    = (const float*)d_in[13];

  char* ws = (char*)d_ws;
  f16*   xs    = (f16*)(ws + XS_OFF);
  f16*   wcat  = (f16*)(ws + WCAT_OFF);
  f16*   wb    = (f16*)(ws + WB_OFF);
  f16*   wpf   = (f16*)(ws + WPF_OFF);
  float* biasf = (float*)(ws + BIASF_OFF);
  float* biasb = (float*)(ws + BIASB_OFF);
  f16*   h0    = (f16*)(ws + H0_OFF);
  f16*   h1    = (f16*)(ws + H1_OFF);
  float* cb    = (float*)(ws + CB_OFF);
  unsigned int* ctr = (unsigned int*)(ws + CTR_OFF);
  f16*   hcatf = (f16*)(ws + HCATF_OFF);
  float* p     = (float*)(ws + P_OFF);

  // zero h0, h1, cb, ctr (contiguous)
  hipMemsetAsync(ws + H0_OFF, 0, (CTR_OFF + 512) - H0_OFF, stream);

  wcat_k<<<(GDIM * KCAT / 8) / 256, 256, 0, stream>>>(wih_f, whh_f, wcat);
  wb_k<<<(GDIM * EDIM / 8) / 256, 256, 0, stream>>>(wih_b, wb);
  cvt8_k<<<(PDIM * 2 * HDIM / 8) / 256, 256, 0, stream>>>(Wp, wpf);
  bias_k<<<(2 * GDIM) / 256, 256, 0, stream>>>(bih_f, bhh_f, bih_b, bhh_b, biasf, biasb);
  embed_k<<<SEQ * BATCH, 64, 0, stream>>>(seq, emb, xs);

  // backward cell collapses to ONE step on xs[0] with zero state; h -> hcat cols [H, 2H)
  lstm_step<<<dim3(4, 64), 256, 0, stream>>>(xs, xs, EDIM, EDIM, EDIM,
      wb, EDIM, biasb, cb, cb, hcatf + HDIM, 2 * HDIM);

  // forward scan: one persistent cooperative kernel, 128 steps
  {
    void* kargs[] = { (void*)&xs, (void*)&wcat, (void*)&biasf, (void*)&h0,
                      (void*)&h1, (void*)&hcatf, (void*)&ctr };
    hipLaunchCooperativeKernel((const void*)lstm_persist, dim3(256), dim3(256),
                               kargs, 0, stream);
  }

  gemmp_k<<<dim3(4, 8), 256, 0, stream>>>(hcatf, wpf, bp, p);
  proj2_k<<<BATCH, 64, 0, stream>>>(p, Wc, bc, (float*)d_out);
}

// Round 5
// 1854.495 us; speedup vs baseline: 2.4509x; 1.0684x over previous
//
#include <hip/hip_runtime.h>

#define BATCH 256
#define SEQ   128
#define EDIM  512
#define HDIM  1024
#define GDIM  4096   // 4*H
#define KCAT  1536   // E + H
#define PDIM  512
#define ODIM  6

typedef _Float16 f16;
typedef _Float16 f16x8 __attribute__((ext_vector_type(8)));
typedef float f32x4 __attribute__((ext_vector_type(4)));

// ---------------- workspace layout (bytes) ----------------
static const size_t XS_OFF    = 0;                                      // f16 [SEQ][BATCH][EDIM]
static const size_t WREP_OFF  = XS_OFF    + (size_t)SEQ*BATCH*EDIM*2;   // f16 repacked fwd W, 12.6 MB
static const size_t WB_OFF    = WREP_OFF  + (size_t)GDIM*KCAT*2;        // f16 [GDIM][EDIM]
static const size_t WPF_OFF   = WB_OFF    + (size_t)GDIM*EDIM*2;        // f16 [PDIM][2*HDIM]
static const size_t BIASF_OFF = WPF_OFF   + (size_t)PDIM*2*HDIM*2;      // f32 [GDIM]
static const size_t BIASB_OFF = BIASF_OFF + (size_t)GDIM*4;             // f32 [GDIM]
// ---- zeroed region start ----
static const size_t H0_OFF    = BIASB_OFF + (size_t)GDIM*4;             // f16 [BATCH][HDIM]
static const size_t H1_OFF    = H0_OFF    + (size_t)BATCH*HDIM*2;       // f16 [BATCH][HDIM]
static const size_t CB_OFF    = H1_OFF    + (size_t)BATCH*HDIM*2;       // f32 [BATCH][HDIM]
static const size_t CTR_OFF   = CB_OFF    + (size_t)BATCH*HDIM*4;       // u32 [4*32]
// ---- zeroed region end (CTR_OFF + 512) ----
static const size_t HCATF_OFF = CTR_OFF   + 512;                        // f16 [BATCH][2*HDIM]
static const size_t P_OFF     = HCATF_OFF + (size_t)BATCH*2*HDIM*2;     // f32 [BATCH][PDIM]

// ---------------- embedding gather + tanh -> f16 ----------------
__global__ __launch_bounds__(64) void embed_k(const int* __restrict__ seq,
                                              const float* __restrict__ emb,
                                              f16* __restrict__ xs) {
  int bid = blockIdx.x;                 // t*256 + b
  int t = bid >> 8, b = bid & 255;
  int tok = seq[b * SEQ + t];
  const float* src = emb + (size_t)tok * EDIM + threadIdx.x * 8;
  f16* dst = xs + (size_t)bid * EDIM + threadIdx.x * 8;
  float4 v0 = *(const float4*)src;
  float4 v1 = *(const float4*)(src + 4);
  f16x8 o;
  o[0] = (f16)tanhf(v0.x); o[1] = (f16)tanhf(v0.y);
  o[2] = (f16)tanhf(v0.z); o[3] = (f16)tanhf(v0.w);
  o[4] = (f16)tanhf(v1.x); o[5] = (f16)tanhf(v1.y);
  o[6] = (f16)tanhf(v1.z); o[7] = (f16)tanhf(v1.w);
  *(f16x8*)dst = o;
}

// ---------------- forward-W repack: per (j-tile, wave, iter, gate) 1KB frags --
// K-chunk map (must match lstm_persist): wave wv, iter i in [0,6):
//   i<2 : x chunk, k = 64*wv + 32*i
//   i>=2: h chunk, k = 512 + 64*wv + 32*((i-2)&1) + 512*((i-2)>>1)
// frag id = ((jt*8 + wv)*6 + i)*4 + g ; layout: frag[lane][8 f16]
__global__ __launch_bounds__(256) void wrep_k(const float* __restrict__ wih,
                                              const float* __restrict__ whh,
                                              f16* __restrict__ wrep) {
  int gid = blockIdx.x * 256 + threadIdx.x;      // 12288 frags * 64 lanes
  int lane = gid & 63;
  int fid = gid >> 6;
  int g = fid & 3;
  int i = (fid >> 2) % 6;
  int wv = (fid / 24) & 7;
  int jt = fid / 192;
  int l15 = lane & 15, l4 = lane >> 4;
  int row = (g << 10) + (jt << 4) + l15;
  int ck = (i < 2) ? (64 * wv + 32 * i)
                   : (512 + 64 * wv + 32 * ((i - 2) & 1) + 512 * ((i - 2) >> 1));
  int k = ck + l4 * 8;
  const float* src = (k < EDIM) ? (wih + (size_t)row * EDIM + k)
                                : (whh + (size_t)row * HDIM + (k - EDIM));
  float4 v0 = *(const float4*)src;
  float4 v1 = *(const float4*)(src + 4);
  f16x8 o;
  o[0] = (f16)v0.x; o[1] = (f16)v0.y; o[2] = (f16)v0.z; o[3] = (f16)v0.w;
  o[4] = (f16)v1.x; o[5] = (f16)v1.y; o[6] = (f16)v1.z; o[7] = (f16)v1.w;
  *(f16x8*)(wrep + (size_t)fid * 512 + lane * 8) = o;
}

__global__ __launch_bounds__(256) void wb_k(const float* __restrict__ wih,
                                            f16* __restrict__ wb) {
  int idx = blockIdx.x * 256 + threadIdx.x;    // EDIM/8 = 64 chunks per row
  int n = idx >> 6, c8 = (idx & 63) * 8;
  const float* src = wih + (size_t)n * EDIM + c8;
  float4 v0 = *(const float4*)src;
  float4 v1 = *(const float4*)(src + 4);
  f16x8 o;
  o[0] = (f16)v0.x; o[1] = (f16)v0.y; o[2] = (f16)v0.z; o[3] = (f16)v0.w;
  o[4] = (f16)v1.x; o[5] = (f16)v1.y; o[6] = (f16)v1.z; o[7] = (f16)v1.w;
  *(f16x8*)(wb + (size_t)n * EDIM + c8) = o;
}

// generic f32 -> f16, 8 elems/thread
__global__ __launch_bounds__(256) void cvt8_k(const float* __restrict__ src,
                                              f16* __restrict__ dst) {
  int idx = blockIdx.x * 256 + threadIdx.x;
  const float* s = src + (size_t)idx * 8;
  float4 v0 = *(const float4*)s;
  float4 v1 = *(const float4*)(s + 4);
  f16x8 o;
  o[0] = (f16)v0.x; o[1] = (f16)v0.y; o[2] = (f16)v0.z; o[3] = (f16)v0.w;
  o[4] = (f16)v1.x; o[5] = (f16)v1.y; o[6] = (f16)v1.z; o[7] = (f16)v1.w;
  *(f16x8*)(dst + (size_t)idx * 8) = o;
}

__global__ __launch_bounds__(256) void bias_k(const float* __restrict__ bih_f,
                                              const float* __restrict__ bhh_f,
                                              const float* __restrict__ bih_b,
                                              const float* __restrict__ bhh_b,
                                              float* __restrict__ biasf,
                                              float* __restrict__ biasb) {
  int i = blockIdx.x * 256 + threadIdx.x;
  if (i < GDIM) biasf[i] = bih_f[i] + bhh_f[i];
  else { int k = i - GDIM; biasb[k] = bih_b[k] + bhh_b[k]; }
}

// ---------------- one-shot LSTM step (backward cell, h0=c0=0) ----------------
__global__ __launch_bounds__(256) void lstm_step(
    const f16* __restrict__ A1, const f16* __restrict__ A2,
    int ld2, int K1, int Ktot,
    const f16* __restrict__ W, int ldw,
    const float* __restrict__ bias,
    const float* cin, float* cout,
    f16* __restrict__ hf16, int ldh)
{
  __shared__ __align__(16) f16 lsA[64 * 136];
  __shared__ __align__(16) f16 lsB[64 * 136];
  __shared__ float lsG[64 * 65];

  int tid = threadIdx.x;
  int m0 = blockIdx.x * 64;
  int j0 = blockIdx.y * 16;
  int w = tid >> 6, lane = tid & 63;
  int wm = (w >> 1) * 32, wn = (w & 1) * 32;
  int l15 = lane & 15, l4 = lane >> 4;

  f32x4 acc[2][2] = {};
  int nk = Ktot >> 7;

  for (int kt = 0; kt < nk; ++kt) {
    int k0 = kt << 7;
    #pragma unroll
    for (int cc = 0; cc < 4; ++cc) {
      int idx = tid + cc * 256;
      int row = idx >> 4, c8 = (idx & 15) << 3;
      int k = k0 + c8;
      const f16* sa = (k < K1) ? (A1 + (size_t)(m0 + row) * EDIM + k)
                               : (A2 + (size_t)(m0 + row) * ld2 + (k - K1));
      *(f16x8*)&lsA[row * 136 + c8] = *(const f16x8*)sa;
      int ng = ((row >> 4) << 10) + j0 + (row & 15);
      *(f16x8*)&lsB[row * 136 + c8] = *(const f16x8*)(W + (size_t)ng * ldw + k);
    }
    __syncthreads();
    #pragma unroll
    for (int ks = 0; ks < 4; ++ks) {
      int ko = ks * 32 + l4 * 8;
      f16x8 a0 = *(const f16x8*)&lsA[(wm + l15) * 136 + ko];
      f16x8 a1 = *(const f16x8*)&lsA[(wm + 16 + l15) * 136 + ko];
      f16x8 b0 = *(const f16x8*)&lsB[(wn + l15) * 136 + ko];
      f16x8 b1 = *(const f16x8*)&lsB[(wn + 16 + l15) * 136 + ko];
      acc[0][0] = __builtin_amdgcn_mfma_f32_16x16x32_f16(a0, b0, acc[0][0], 0, 0, 0);
      acc[0][1] = __builtin_amdgcn_mfma_f32_16x16x32_f16(a0, b1, acc[0][1], 0, 0, 0);
      acc[1][0] = __builtin_amdgcn_mfma_f32_16x16x32_f16(a1, b0, acc[1][0], 0, 0, 0);
      acc[1][1] = __builtin_amdgcn_mfma_f32_16x16x32_f16(a1, b1, acc[1][1], 0, 0, 0);
    }
    __syncthreads();
  }

  #pragma unroll
  for (int mi = 0; mi < 2; ++mi)
    #pragma unroll
    for (int ni = 0; ni < 2; ++ni) {
      int col = wn + ni * 16 + l15;
      int mr = wm + mi * 16 + l4 * 4;
      #pragma unroll
      for (int r = 0; r < 4; ++r)
        lsG[(mr + r) * 65 + col] = acc[mi][ni][r];
    }
  __syncthreads();

  int jl = tid & 15, mb = tid >> 4;
  int j = j0 + jl;
  #pragma unroll
  for (int mm = 0; mm < 4; ++mm) {
    int ml = mb + mm * 16;
    int m = m0 + ml;
    float gi = lsG[ml * 65 +      jl] + bias[j];
    float gf = lsG[ml * 65 + 16 + jl] + bias[HDIM + j];
    float gg = lsG[ml * 65 + 32 + jl] + bias[2 * HDIM + j];
    float go = lsG[ml * 65 + 48 + jl] + bias[3 * HDIM + j];
    float si = 1.f / (1.f + __expf(-gi));
    float sf = 1.f / (1.f + __expf(-gf));
    float so = 1.f / (1.f + __expf(-go));
    float c  = sf * cin[m * HDIM + j] + si * tanhf(gg);
    cout[m * HDIM + j] = c;
    float h = so * tanhf(c);
    hf16[(size_t)m * ldh + j] = (f16)h;
  }
}

// device-coherent (sc1) h fragment load: 2 x relaxed agent-scope b64 atomics.
__device__ __forceinline__ f16x8 load_h_sc(const f16* p) {
  const unsigned long long* q = (const unsigned long long*)p;
  union { unsigned long long u[2]; f16x8 v; } r;
  r.u[0] = __hip_atomic_load(q,     __ATOMIC_RELAXED, __HIP_MEMORY_SCOPE_AGENT);
  r.u[1] = __hip_atomic_load(q + 1, __ATOMIC_RELAXED, __HIP_MEMORY_SCOPE_AGENT);
  return r.v;
}

// ---------------- persistent forward scan (fence-free, 8 waves) ----------------
// 256 WGs cooperative x 512 threads (8 waves, 2/SIMD). chain = wg>>6
// (m0 = chain*64), j0 = (wg&63)*16. Wave wv owns K-slice of 192 (map above).
// Per step: issue all x (2 iters) + h (4 iters) A-frag loads upfront, stream
// repacked W double-buffered, 16 MFMA/iter, 8-way LDS reduction + pointwise.
// h exchange via sc1 relaxed atomics; barrier = vmcnt(0) + per-chain counter.
__global__ __launch_bounds__(512, 2) void lstm_persist(
    const f16* __restrict__ xs, const f16* __restrict__ wrep,
    const float* __restrict__ bias,
    f16* h0, f16* h1, f16* __restrict__ hcat,
    unsigned int* __restrict__ ctr)
{
  __shared__ float lsR[8][64][66];       // 135168 B
  __shared__ unsigned int sTok;
  int tid = threadIdx.x;
  int wg = blockIdx.x;
  int chain = wg >> 6;
  int m0 = chain << 6;
  int j0 = (wg & 63) << 4;
  int wv = tid >> 6, lane = tid & 63;
  int l15 = lane & 15, l4 = lane >> 4;

  // per-thread W fragment base (contiguous 24 frags x 1KB per wave)
  const f16* wbase = wrep + ((size_t)((wg & 63) * 8 + wv) * 24) * 512 + lane * 8;

  int kb = 64 * wv + l4 * 8;             // wave-base k offset (elements)
  size_t offX[4], offH[4];
  #pragma unroll
  for (int ms = 0; ms < 4; ++ms) {
    int row = m0 + ms * 16 + l15;
    offX[ms] = (size_t)row * EDIM + kb;
    offH[ms] = (size_t)row * HDIM + kb;
  }

  int jl = tid & 15, mb = tid >> 4;      // mb in [0,32)
  float creg[2] = {0.f, 0.f};
  float bg[4];
  #pragma unroll
  for (int g = 0; g < 4; ++g) bg[g] = bias[(g << 10) + j0 + jl];

  unsigned int* mctr = ctr + chain * 32; // 128 B apart per chain
  size_t guard = 0;

  #pragma unroll 1
  for (int t = 0; t < SEQ; ++t) {
    const f16* xtg = xs + (size_t)t * BATCH * EDIM + guard;
    const f16* hpg = ((t & 1) ? h1 : h0) + guard;
    f16* hn = (t & 1) ? h0 : h1;

    // ---- issue ALL A-fragment loads upfront ----
    f16x8 xa[2][4], ha[4][4];
    #pragma unroll
    for (int d = 0; d < 2; ++d)
      #pragma unroll
      for (int ms = 0; ms < 4; ++ms)
        xa[d][ms] = *(const f16x8*)(xtg + offX[ms] + 32 * d);
    #pragma unroll
    for (int q = 0; q < 4; ++q)
      #pragma unroll
      for (int ms = 0; ms < 4; ++ms)
        ha[q][ms] = load_h_sc(hpg + offH[ms] + 32 * (q & 1) + 512 * (q >> 1));

    // ---- MFMA over 6 iters, W double-buffered ----
    f32x4 acc[4][4] = {};                // [gate][m-sub]
    f16x8 wbuf[2][4];
    #pragma unroll
    for (int g = 0; g < 4; ++g)
      wbuf[0][g] = *(const f16x8*)(wbase + (size_t)g * 512);
    #pragma unroll
    for (int i = 0; i < 6; ++i) {
      if (i < 5) {
        #pragma unroll
        for (int g = 0; g < 4; ++g)
          wbuf[(i + 1) & 1][g] = *(const f16x8*)(wbase + (size_t)((i + 1) * 4 + g) * 512);
      }
      #pragma unroll
      for (int g = 0; g < 4; ++g)
        #pragma unroll
        for (int ms = 0; ms < 4; ++ms)
          acc[g][ms] = __builtin_amdgcn_mfma_f32_16x16x32_f16(
              (i < 2) ? xa[i][ms] : ha[i - 2][ms], wbuf[i & 1][g], acc[g][ms], 0, 0, 0);
    }

    // ---- cross-wave K reduction (C/D: row = l4*4+r, col = l15) ----
    #pragma unroll
    for (int g = 0; g < 4; ++g)
      #pragma unroll
      for (int ms = 0; ms < 4; ++ms)
        #pragma unroll
        for (int r = 0; r < 4; ++r)
          lsR[wv][ms * 16 + l4 * 4 + r][g * 16 + l15] = acc[g][ms][r];
    __syncthreads();

    // ---- pointwise: 512 threads x 2 rows each ----
    #pragma unroll
    for (int mm = 0; mm < 2; ++mm) {
      int ml = mb + (mm << 5);
      int m = m0 + ml;
      float ga[4];
      #pragma unroll
      for (int g = 0; g < 4; ++g) {
        float s = bg[g];
        #pragma unroll
        for (int u = 0; u < 8; ++u) s += lsR[u][ml][g * 16 + jl];
        ga[g] = s;
      }
      float si = 1.f / (1.f + __expf(-ga[0]));
      float sf = 1.f / (1.f + __expf(-ga[1]));
      float so = 1.f / (1.f + __expf(-ga[3]));
      float c = sf * creg[mm] + si * tanhf(ga[2]);
      creg[mm] = c;
      float h = so * tanhf(c);
      float hx = __shfl_xor(h, 1);
      if ((jl & 1) == 0) {
        union { f16 h2[2]; unsigned int u; } pk;
        pk.h2[0] = (f16)h; pk.h2[1] = (f16)hx;
        __hip_atomic_store((unsigned int*)(hn + (size_t)m * HDIM + j0 + jl), pk.u,
                           __ATOMIC_RELAXED, __HIP_MEMORY_SCOPE_AGENT);
      }
      if (t == SEQ - 1) hcat[(size_t)m * (2 * HDIM) + j0 + jl] = (f16)h;
    }

    if (t < SEQ - 1) {
      // drain sc1 stores to the coherence point, then arrive + wait (chain-local)
      asm volatile("s_waitcnt vmcnt(0)" ::: "memory");
      __syncthreads();
      if (tid == 0) {
        __hip_atomic_fetch_add(mctr, 1u, __ATOMIC_RELAXED, __HIP_MEMORY_SCOPE_AGENT);
        unsigned int tgt = 64u * (unsigned int)(t + 1);
        unsigned int obs = __hip_atomic_load(mctr, __ATOMIC_RELAXED, __HIP_MEMORY_SCOPE_AGENT);
        unsigned int spins = 0;
        while (obs < tgt && spins < (1u << 20)) {   // watchdog: fail visibly, never hang
          __builtin_amdgcn_s_sleep(1);
          obs = __hip_atomic_load(mctr, __ATOMIC_RELAXED, __HIP_MEMORY_SCOPE_AGENT);
          ++spins;
        }
        sTok = obs;
      }
      __syncthreads();
      guard = (size_t)(sTok >> 31);      // always 0; forces dependency order
    }
  }
}

// ---------------- p = hcat @ Wp^T + bp via MFMA (f16 in, f32 out) ----------------
__global__ __launch_bounds__(256) void gemmp_k(const f16* __restrict__ A,
                                               const f16* __restrict__ B,
                                               const float* __restrict__ bias,
                                               float* __restrict__ out) {
  __shared__ __align__(16) f16 lsA[64 * 136];
  __shared__ __align__(16) f16 lsB[64 * 136];
  int tid = threadIdx.x;
  int m0 = blockIdx.x * 64, n0 = blockIdx.y * 64;
  int w = tid >> 6, lane = tid & 63;
  int wm = (w >> 1) * 32, wn = (w & 1) * 32;
  int l15 = lane & 15, l4 = lane >> 4;
  f32x4 acc[2][2] = {};
  for (int kt = 0; kt < 16; ++kt) {            // K = 2048
    int k0 = kt << 7;
    #pragma unroll
    for (int cc = 0; cc < 4; ++cc) {
      int idx = tid + cc * 256;
      int row = idx >> 4, c8 = (idx & 15) << 3;
      *(f16x8*)&lsA[row * 136 + c8] = *(const f16x8*)(A + (size_t)(m0 + row) * (2 * HDIM) + k0 + c8);
      *(f16x8*)&lsB[row * 136 + c8] = *(const f16x8*)(B + (size_t)(n0 + row) * (2 * HDIM) + k0 + c8);
    }
    __syncthreads();
    #pragma unroll
    for (int ks = 0; ks < 4; ++ks) {
      int ko = ks * 32 + l4 * 8;
      f16x8 a0 = *(const f16x8*)&lsA[(wm + l15) * 136 + ko];
      f16x8 a1 = *(const f16x8*)&lsA[(wm + 16 + l15) * 136 + ko];
      f16x8 b0 = *(const f16x8*)&lsB[(wn + l15) * 136 + ko];
      f16x8 b1 = *(const f16x8*)&lsB[(wn + 16 + l15) * 136 + ko];
      acc[0][0] = __builtin_amdgcn_mfma_f32_16x16x32_f16(a0, b0, acc[0][0], 0, 0, 0);
      acc[0][1] = __builtin_amdgcn_mfma_f32_16x16x32_f16(a0, b1, acc[0][1], 0, 0, 0);
      acc[1][0] = __builtin_amdgcn_mfma_f32_16x16x32_f16(a1, b0, acc[1][0], 0, 0, 0);
      acc[1][1] = __builtin_amdgcn_mfma_f32_16x16x32_f16(a1, b1, acc[1][1], 0, 0, 0);
    }
    __syncthreads();
  }
  #pragma unroll
  for (int mi = 0; mi < 2; ++mi)
    #pragma unroll
    for (int ni = 0; ni < 2; ++ni)
      #pragma unroll
      for (int r = 0; r < 4; ++r) {
        int m = m0 + wm + mi * 16 + l4 * 4 + r;
        int n = n0 + wn + ni * 16 + l15;
        out[(size_t)m * PDIM + n] = acc[mi][ni][r] + bias[n];
      }
}

// ---------------- out = sigmoid(p @ Wc^T + bc) ----------------
__global__ __launch_bounds__(64) void proj2_k(const float* __restrict__ p,
                                              const float* __restrict__ Wc,
                                              const float* __restrict__ bc,
                                              float* __restrict__ out) {
  int m = blockIdx.x, l = threadIdx.x;
  float pv[8];
  #pragma unroll
  for (int q = 0; q < 8; ++q) pv[q] = p[(size_t)m * PDIM + l + 64 * q];
  #pragma unroll
  for (int c = 0; c < ODIM; ++c) {
    float s = 0.f;
    #pragma unroll
    for (int q = 0; q < 8; ++q) s += pv[q] * Wc[c * PDIM + l + 64 * q];
    #pragma unroll
    for (int off = 32; off > 0; off >>= 1) s += __shfl_down(s, off);
    if (l == 0) out[m * ODIM + c] = 1.f / (1.f + __expf(-(s + bc[c])));
  }
}

extern "C" void kernel_launch(void* const* d_in, const int* in_sizes, int n_in,
                              void* d_out, int out_size, void* d_ws, size_t ws_size,
                              hipStream_t stream) {
  const int*   seq   = (const int*)d_in[0];
  const float* emb   = (const float*)d_in[1];
  const float* wih_f = (const float*)d_in[2];
  const float* whh_f = (const float*)d_in[3];
  const float* bih_f = (const float*)d_in[4];
  const float* bhh_f = (const float*)d_in[5];
  const float* wih_b = (const float*)d_in[6];
  const float* bih_b = (const float*)d_in[8];
  const float* bhh_b = (const float*)d_in[9];
  const float* Wp    = (const float*)d_in[10];
  const float* bp    = (const float*)d_in[11];
  const float* Wc    = (const float*)d_in[12];
  const float* bc    = (const float*)d_in[13];

  char* ws = (char*)d_ws;
  f16*   xs    = (f16*)(ws + XS_OFF);
  f16*   wrep  = (f16*)(ws + WREP_OFF);
  f16*   wb    = (f16*)(ws + WB_OFF);
  f16*   wpf   = (f16*)(ws + WPF_OFF);
  float* biasf = (float*)(ws + BIASF_OFF);
  float* biasb = (float*)(ws + BIASB_OFF);
  f16*   h0    = (f16*)(ws + H0_OFF);
  f16*   h1    = (f16*)(ws + H1_OFF);
  float* cb    = (float*)(ws + CB_OFF);
  unsigned int* ctr = (unsigned int*)(ws + CTR_OFF);
  f16*   hcatf = (f16*)(ws + HCATF_OFF);
  float* p     = (float*)(ws + P_OFF);

  // zero h0, h1, cb, ctr (contiguous)
  hipMemsetAsync(ws + H0_OFF, 0, (CTR_OFF + 512) - H0_OFF, stream);

  wrep_k<<<(GDIM * KCAT / 8) / 256, 256, 0, stream>>>(wih_f, whh_f, wrep);
  wb_k<<<(GDIM * EDIM / 8) / 256, 256, 0, stream>>>(wih_b, wb);
  cvt8_k<<<(PDIM * 2 * HDIM / 8) / 256, 256, 0, stream>>>(Wp, wpf);
  bias_k<<<(2 * GDIM) / 256, 256, 0, stream>>>(bih_f, bhh_f, bih_b, bhh_b, biasf, biasb);
  embed_k<<<SEQ * BATCH, 64, 0, stream>>>(seq, emb, xs);

  // backward cell collapses to ONE step on xs[0] with zero state; h -> hcat cols [H, 2H)
  lstm_step<<<dim3(4, 64), 256, 0, stream>>>(xs, xs, EDIM, EDIM, EDIM,
      wb, EDIM, biasb, cb, cb, hcatf + HDIM, 2 * HDIM);

  // forward scan: one persistent cooperative kernel, 128 steps
  {
    void* kargs[] = { (void*)&xs, (void*)&wrep, (void*)&biasf, (void*)&h0,
                      (void*)&h1, (void*)&hcatf, (void*)&ctr };
    hipLaunchCooperativeKernel((const void*)lstm_persist, dim3(256), dim3(512),
                               kargs, 0, stream);
  }

  gemmp_k<<<dim3(4, 8), 256, 0, stream>>>(hcatf, wpf, bp, p);
  proj2_k<<<BATCH, 64, 0, stream>>>(p, Wc, bc, (float*)d_out);
}

// Round 6
// 1852.008 us; speedup vs baseline: 2.4542x; 1.0013x over previous
//
#include <hip/hip_runtime.h>

#define BATCH 256
#define SEQ   128
#define EDIM  512
#define HDIM  1024
#define GDIM  4096   // 4*H
#define KCAT  1536   // E + H
#define PDIM  512
#define ODIM  6

typedef _Float16 f16;
typedef _Float16 f16x8 __attribute__((ext_vector_type(8)));
typedef float f32x4 __attribute__((ext_vector_type(4)));

// ---------------- workspace layout (bytes) ----------------
static const size_t XS_OFF    = 0;                                      // f16 [SEQ][BATCH][EDIM]
static const size_t WREP_OFF  = XS_OFF    + (size_t)SEQ*BATCH*EDIM*2;   // f16 repacked fwd W, 12.6 MB
static const size_t WB_OFF    = WREP_OFF  + (size_t)GDIM*KCAT*2;        // f16 [GDIM][EDIM]
static const size_t WPF_OFF   = WB_OFF    + (size_t)GDIM*EDIM*2;        // f16 [PDIM][2*HDIM]
static const size_t BIASF_OFF = WPF_OFF   + (size_t)PDIM*2*HDIM*2;      // f32 [GDIM]
static const size_t BIASB_OFF = BIASF_OFF + (size_t)GDIM*4;             // f32 [GDIM]
// ---- zeroed region start ----
static const size_t H0_OFF    = BIASB_OFF + (size_t)GDIM*4;             // f16 [BATCH][HDIM]
static const size_t H1_OFF    = H0_OFF    + (size_t)BATCH*HDIM*2;       // f16 [BATCH][HDIM]
static const size_t CB_OFF    = H1_OFF    + (size_t)BATCH*HDIM*2;       // f32 [BATCH][HDIM]
static const size_t FLG_OFF   = CB_OFF    + (size_t)BATCH*HDIM*4;       // u32 [4][64] flags
// ---- zeroed region end (FLG_OFF + 1024) ----
static const size_t HCATF_OFF = FLG_OFF   + 1024;                       // f16 [BATCH][2*HDIM]
static const size_t P_OFF     = HCATF_OFF + (size_t)BATCH*2*HDIM*2;     // f32 [BATCH][PDIM]

// ---------------- embedding gather + tanh -> f16 ----------------
__global__ __launch_bounds__(64) void embed_k(const int* __restrict__ seq,
                                              const float* __restrict__ emb,
                                              f16* __restrict__ xs) {
  int bid = blockIdx.x;                 // t*256 + b
  int t = bid >> 8, b = bid & 255;
  int tok = seq[b * SEQ + t];
  const float* src = emb + (size_t)tok * EDIM + threadIdx.x * 8;
  f16* dst = xs + (size_t)bid * EDIM + threadIdx.x * 8;
  float4 v0 = *(const float4*)src;
  float4 v1 = *(const float4*)(src + 4);
  f16x8 o;
  o[0] = (f16)tanhf(v0.x); o[1] = (f16)tanhf(v0.y);
  o[2] = (f16)tanhf(v0.z); o[3] = (f16)tanhf(v0.w);
  o[4] = (f16)tanhf(v1.x); o[5] = (f16)tanhf(v1.y);
  o[6] = (f16)tanhf(v1.z); o[7] = (f16)tanhf(v1.w);
  *(f16x8*)dst = o;
}

// ---------------- forward-W repack: per (j-tile, wave, iter, gate) 1KB frags --
// K-chunk map (must match lstm_persist): wave wv, iter i in [0,6):
//   i<2 : x chunk, k = 64*wv + 32*i
//   i>=2: h chunk, k = 512 + 64*wv + 32*((i-2)&1) + 512*((i-2)>>1)
// frag id = ((jt*8 + wv)*6 + i)*4 + g ; layout: frag[lane][8 f16]
__global__ __launch_bounds__(256) void wrep_k(const float* __restrict__ wih,
                                              const float* __restrict__ whh,
                                              f16* __restrict__ wrep) {
  int gid = blockIdx.x * 256 + threadIdx.x;      // 12288 frags * 64 lanes
  int lane = gid & 63;
  int fid = gid >> 6;
  int g = fid & 3;
  int i = (fid >> 2) % 6;
  int wv = (fid / 24) & 7;
  int jt = fid / 192;
  int l15 = lane & 15, l4 = lane >> 4;
  int row = (g << 10) + (jt << 4) + l15;
  int ck = (i < 2) ? (64 * wv + 32 * i)
                   : (512 + 64 * wv + 32 * ((i - 2) & 1) + 512 * ((i - 2) >> 1));
  int k = ck + l4 * 8;
  const float* src = (k < EDIM) ? (wih + (size_t)row * EDIM + k)
                                : (whh + (size_t)row * HDIM + (k - EDIM));
  float4 v0 = *(const float4*)src;
  float4 v1 = *(const float4*)(src + 4);
  f16x8 o;
  o[0] = (f16)v0.x; o[1] = (f16)v0.y; o[2] = (f16)v0.z; o[3] = (f16)v0.w;
  o[4] = (f16)v1.x; o[5] = (f16)v1.y; o[6] = (f16)v1.z; o[7] = (f16)v1.w;
  *(f16x8*)(wrep + (size_t)fid * 512 + lane * 8) = o;
}

__global__ __launch_bounds__(256) void wb_k(const float* __restrict__ wih,
                                            f16* __restrict__ wb) {
  int idx = blockIdx.x * 256 + threadIdx.x;    // EDIM/8 = 64 chunks per row
  int n = idx >> 6, c8 = (idx & 63) * 8;
  const float* src = wih + (size_t)n * EDIM + c8;
  float4 v0 = *(const float4*)src;
  float4 v1 = *(const float4*)(src + 4);
  f16x8 o;
  o[0] = (f16)v0.x; o[1] = (f16)v0.y; o[2] = (f16)v0.z; o[3] = (f16)v0.w;
  o[4] = (f16)v1.x; o[5] = (f16)v1.y; o[6] = (f16)v1.z; o[7] = (f16)v1.w;
  *(f16x8*)(wb + (size_t)n * EDIM + c8) = o;
}

// generic f32 -> f16, 8 elems/thread
__global__ __launch_bounds__(256) void cvt8_k(const float* __restrict__ src,
                                              f16* __restrict__ dst) {
  int idx = blockIdx.x * 256 + threadIdx.x;
  const float* s = src + (size_t)idx * 8;
  float4 v0 = *(const float4*)s;
  float4 v1 = *(const float4*)(s + 4);
  f16x8 o;
  o[0] = (f16)v0.x; o[1] = (f16)v0.y; o[2] = (f16)v0.z; o[3] = (f16)v0.w;
  o[4] = (f16)v1.x; o[5] = (f16)v1.y; o[6] = (f16)v1.z; o[7] = (f16)v1.w;
  *(f16x8*)(dst + (size_t)idx * 8) = o;
}

__global__ __launch_bounds__(256) void bias_k(const float* __restrict__ bih_f,
                                              const float* __restrict__ bhh_f,
                                              const float* __restrict__ bih_b,
                                              const float* __restrict__ bhh_b,
                                              float* __restrict__ biasf,
                                              float* __restrict__ biasb) {
  int i = blockIdx.x * 256 + threadIdx.x;
  if (i < GDIM) biasf[i] = bih_f[i] + bhh_f[i];
  else { int k = i - GDIM; biasb[k] = bih_b[k] + bhh_b[k]; }
}

// ---------------- one-shot LSTM step (backward cell, h0=c0=0) ----------------
__global__ __launch_bounds__(256) void lstm_step(
    const f16* __restrict__ A1, const f16* __restrict__ A2,
    int ld2, int K1, int Ktot,
    const f16* __restrict__ W, int ldw,
    const float* __restrict__ bias,
    const float* cin, float* cout,
    f16* __restrict__ hf16, int ldh)
{
  __shared__ __align__(16) f16 lsA[64 * 136];
  __shared__ __align__(16) f16 lsB[64 * 136];
  __shared__ float lsG[64 * 65];

  int tid = threadIdx.x;
  int m0 = blockIdx.x * 64;
  int j0 = blockIdx.y * 16;
  int w = tid >> 6, lane = tid & 63;
  int wm = (w >> 1) * 32, wn = (w & 1) * 32;
  int l15 = lane & 15, l4 = lane >> 4;

  f32x4 acc[2][2] = {};
  int nk = Ktot >> 7;

  for (int kt = 0; kt < nk; ++kt) {
    int k0 = kt << 7;
    #pragma unroll
    for (int cc = 0; cc < 4; ++cc) {
      int idx = tid + cc * 256;
      int row = idx >> 4, c8 = (idx & 15) << 3;
      int k = k0 + c8;
      const f16* sa = (k < K1) ? (A1 + (size_t)(m0 + row) * EDIM + k)
                               : (A2 + (size_t)(m0 + row) * ld2 + (k - K1));
      *(f16x8*)&lsA[row * 136 + c8] = *(const f16x8*)sa;
      int ng = ((row >> 4) << 10) + j0 + (row & 15);
      *(f16x8*)&lsB[row * 136 + c8] = *(const f16x8*)(W + (size_t)ng * ldw + k);
    }
    __syncthreads();
    #pragma unroll
    for (int ks = 0; ks < 4; ++ks) {
      int ko = ks * 32 + l4 * 8;
      f16x8 a0 = *(const f16x8*)&lsA[(wm + l15) * 136 + ko];
      f16x8 a1 = *(const f16x8*)&lsA[(wm + 16 + l15) * 136 + ko];
      f16x8 b0 = *(const f16x8*)&lsB[(wn + l15) * 136 + ko];
      f16x8 b1 = *(const f16x8*)&lsB[(wn + 16 + l15) * 136 + ko];
      acc[0][0] = __builtin_amdgcn_mfma_f32_16x16x32_f16(a0, b0, acc[0][0], 0, 0, 0);
      acc[0][1] = __builtin_amdgcn_mfma_f32_16x16x32_f16(a0, b1, acc[0][1], 0, 0, 0);
      acc[1][0] = __builtin_amdgcn_mfma_f32_16x16x32_f16(a1, b0, acc[1][0], 0, 0, 0);
      acc[1][1] = __builtin_amdgcn_mfma_f32_16x16x32_f16(a1, b1, acc[1][1], 0, 0, 0);
    }
    __syncthreads();
  }

  #pragma unroll
  for (int mi = 0; mi < 2; ++mi)
    #pragma unroll
    for (int ni = 0; ni < 2; ++ni) {
      int col = wn + ni * 16 + l15;
      int mr = wm + mi * 16 + l4 * 4;
      #pragma unroll
      for (int r = 0; r < 4; ++r)
        lsG[(mr + r) * 65 + col] = acc[mi][ni][r];
    }
  __syncthreads();

  int jl = tid & 15, mb = tid >> 4;
  int j = j0 + jl;
  #pragma unroll
  for (int mm = 0; mm < 4; ++mm) {
    int ml = mb + mm * 16;
    int m = m0 + ml;
    float gi = lsG[ml * 65 +      jl] + bias[j];
    float gf = lsG[ml * 65 + 16 + jl] + bias[HDIM + j];
    float gg = lsG[ml * 65 + 32 + jl] + bias[2 * HDIM + j];
    float go = lsG[ml * 65 + 48 + jl] + bias[3 * HDIM + j];
    float si = 1.f / (1.f + __expf(-gi));
    float sf = 1.f / (1.f + __expf(-gf));
    float so = 1.f / (1.f + __expf(-go));
    float c  = sf * cin[m * HDIM + j] + si * tanhf(gg);
    cout[m * HDIM + j] = c;
    float h = so * tanhf(c);
    hf16[(size_t)m * ldh + j] = (f16)h;
  }
}

// device-coherent (sc1) h fragment load: 2 x relaxed agent-scope b64 atomics.
__device__ __forceinline__ f16x8 load_h_sc(const f16* p) {
  const unsigned long long* q = (const unsigned long long*)p;
  union { unsigned long long u[2]; f16x8 v; } r;
  r.u[0] = __hip_atomic_load(q,     __ATOMIC_RELAXED, __HIP_MEMORY_SCOPE_AGENT);
  r.u[1] = __hip_atomic_load(q + 1, __ATOMIC_RELAXED, __HIP_MEMORY_SCOPE_AGENT);
  return r.v;
}

// ---------------- persistent forward scan (flag barrier + pipeline skew) -----
// 256 WGs cooperative x 512 threads. chain = wg>>6 (m0=chain*64), j0=(wg&63)*16.
// Per step: [poll 64 flags via wave0 lanes, one RTT] -> h loads + 4 h-MFMA
// iters -> LDS reduce -> pointwise -> sc1 h store -> vmcnt drain -> flag
// STORE (no RMW) -> x-phase of t+1 (2 MFMA iters, h-independent) under the
// barrier shadow. sched_barrier pins x-phase before the poll.
__global__ __launch_bounds__(512, 1) void lstm_persist(
    const f16* __restrict__ xs, const f16* __restrict__ wrep,
    const float* __restrict__ bias,
    f16* h0, f16* h1, f16* __restrict__ hcat,
    unsigned int* __restrict__ flags)
{
  __shared__ float lsR[8][64][66];       // 135168 B
  __shared__ unsigned int sTok;
  int tid = threadIdx.x;
  int wg = blockIdx.x;
  int chain = wg >> 6;
  int m0 = chain << 6;
  int wgj = wg & 63;
  int j0 = wgj << 4;
  int wv = tid >> 6, lane = tid & 63;
  int l15 = lane & 15, l4 = lane >> 4;

  // per-thread W fragment base (contiguous 24 frags x 1KB per wave)
  const f16* wbase = wrep + ((size_t)(wgj * 8 + wv) * 24) * 512 + lane * 8;

  int kb = 64 * wv + l4 * 8;             // wave-base k offset (elements)
  size_t offX[4], offH[4];
  #pragma unroll
  for (int ms = 0; ms < 4; ++ms) {
    int row = m0 + ms * 16 + l15;
    offX[ms] = (size_t)row * EDIM + kb;
    offH[ms] = (size_t)row * HDIM + kb;
  }

  int jl = tid & 15, mb = tid >> 4;      // mb in [0,32)
  float creg[2] = {0.f, 0.f};
  float bg[4];
  #pragma unroll
  for (int g = 0; g < 4; ++g) bg[g] = bias[(g << 10) + j0 + jl];

  unsigned int* mflag = flags + chain * 64;   // 64 slots (256 B) per chain

  f32x4 acc[4][4];                       // [gate][m-sub]
  f16x8 xa[2][4], ha[4][4];
  f16x8 wb0[4], wb1[4], wb2[4], wb3[4];

// x-phase: load x frags + first 3 W groups, run iters 0-1 (zero-init folded
// into iter0 via zero C operand). h-independent -> runs under barrier shadow.
#define XPHASE(TT)                                                             \
  {                                                                            \
    const f16* xtg = xs + (size_t)(TT) * BATCH * EDIM;                         \
    _Pragma("unroll") for (int g = 0; g < 4; ++g) {                            \
      wb0[g] = *(const f16x8*)(wbase + (size_t)(0 * 4 + g) * 512);             \
      wb1[g] = *(const f16x8*)(wbase + (size_t)(1 * 4 + g) * 512);             \
      wb2[g] = *(const f16x8*)(wbase + (size_t)(2 * 4 + g) * 512);             \
    }                                                                          \
    _Pragma("unroll") for (int d = 0; d < 2; ++d)                              \
      _Pragma("unroll") for (int ms = 0; ms < 4; ++ms)                         \
        xa[d][ms] = *(const f16x8*)(xtg + offX[ms] + 32 * d);                  \
    _Pragma("unroll") for (int g = 0; g < 4; ++g)                              \
      _Pragma("unroll") for (int ms = 0; ms < 4; ++ms)                         \
        acc[g][ms] = __builtin_amdgcn_mfma_f32_16x16x32_f16(                   \
            xa[0][ms], wb0[g], f32x4{0.f, 0.f, 0.f, 0.f}, 0, 0, 0);            \
    _Pragma("unroll") for (int g = 0; g < 4; ++g)                              \
      _Pragma("unroll") for (int ms = 0; ms < 4; ++ms)                         \
        acc[g][ms] = __builtin_amdgcn_mfma_f32_16x16x32_f16(                   \
            xa[1][ms], wb1[g], acc[g][ms], 0, 0, 0);                           \
  }

  XPHASE(0)

  #pragma unroll 1
  for (int t = 0; t < SEQ; ++t) {
    // ---- wait for h(t-1): wave0 lanes read all 64 flags, one RTT ----
    size_t hg = 0;
    if (t > 0) {
      if (tid < 64) {
        unsigned int tgt = (unsigned int)t;
        unsigned int obs = 0, spins = 0;
        do {
          obs = __hip_atomic_load(mflag + tid, __ATOMIC_RELAXED, __HIP_MEMORY_SCOPE_AGENT);
          ++spins;
        } while (!__all((int)(obs >= tgt)) && spins < (1u << 18));  // watchdog
        if (tid == 0) sTok = obs;
      }
      __syncthreads();
      hg = (size_t)(sTok >> 31);         // always 0; data-dependency fence
    }
    const f16* hpg = ((t & 1) ? h1 : h0) + hg;
    f16* hn = (t & 1) ? h0 : h1;

    // ---- h-phase: staged sc1 loads interleaved with W dbuf + 4 MFMA iters --
    #pragma unroll
    for (int q = 0; q < 2; ++q)
      #pragma unroll
      for (int ms = 0; ms < 4; ++ms)
        ha[q][ms] = load_h_sc(hpg + offH[ms] + 32 * q);
    #pragma unroll
    for (int g = 0; g < 4; ++g)
      wb3[g] = *(const f16x8*)(wbase + (size_t)(3 * 4 + g) * 512);
    #pragma unroll
    for (int g = 0; g < 4; ++g)
      #pragma unroll
      for (int ms = 0; ms < 4; ++ms)
        acc[g][ms] = __builtin_amdgcn_mfma_f32_16x16x32_f16(ha[0][ms], wb2[g], acc[g][ms], 0, 0, 0);
    #pragma unroll
    for (int q = 2; q < 4; ++q)
      #pragma unroll
      for (int ms = 0; ms < 4; ++ms)
        ha[q][ms] = load_h_sc(hpg + offH[ms] + 32 * (q & 1) + 512);
    #pragma unroll
    for (int g = 0; g < 4; ++g)
      wb0[g] = *(const f16x8*)(wbase + (size_t)(4 * 4 + g) * 512);
    #pragma unroll
    for (int g = 0; g < 4; ++g)
      #pragma unroll
      for (int ms = 0; ms < 4; ++ms)
        acc[g][ms] = __builtin_amdgcn_mfma_f32_16x16x32_f16(ha[1][ms], wb3[g], acc[g][ms], 0, 0, 0);
    #pragma unroll
    for (int g = 0; g < 4; ++g)
      wb1[g] = *(const f16x8*)(wbase + (size_t)(5 * 4 + g) * 512);
    #pragma unroll
    for (int g = 0; g < 4; ++g)
      #pragma unroll
      for (int ms = 0; ms < 4; ++ms)
        acc[g][ms] = __builtin_amdgcn_mfma_f32_16x16x32_f16(ha[2][ms], wb0[g], acc[g][ms], 0, 0, 0);
    #pragma unroll
    for (int g = 0; g < 4; ++g)
      #pragma unroll
      for (int ms = 0; ms < 4; ++ms)
        acc[g][ms] = __builtin_amdgcn_mfma_f32_16x16x32_f16(ha[3][ms], wb1[g], acc[g][ms], 0, 0, 0);

    // ---- cross-wave K reduction (C/D: row = l4*4+r, col = l15) ----
    #pragma unroll
    for (int g = 0; g < 4; ++g)
      #pragma unroll
      for (int ms = 0; ms < 4; ++ms)
        #pragma unroll
        for (int r = 0; r < 4; ++r)
          lsR[wv][ms * 16 + l4 * 4 + r][g * 16 + l15] = acc[g][ms][r];
    __syncthreads();

    // ---- pointwise: 512 threads x 2 rows each ----
    #pragma unroll
    for (int mm = 0; mm < 2; ++mm) {
      int ml = mb + (mm << 5);
      int m = m0 + ml;
      float ga[4];
      #pragma unroll
      for (int g = 0; g < 4; ++g) {
        float s = bg[g];
        #pragma unroll
        for (int u = 0; u < 8; ++u) s += lsR[u][ml][g * 16 + jl];
        ga[g] = s;
      }
      float si = 1.f / (1.f + __expf(-ga[0]));
      float sf = 1.f / (1.f + __expf(-ga[1]));
      float so = 1.f / (1.f + __expf(-ga[3]));
      float c = sf * creg[mm] + si * tanhf(ga[2]);
      creg[mm] = c;
      float h = so * tanhf(c);
      float hx = __shfl_xor(h, 1);
      if ((jl & 1) == 0) {
        union { f16 h2[2]; unsigned int u; } pk;
        pk.h2[0] = (f16)h; pk.h2[1] = (f16)hx;
        __hip_atomic_store((unsigned int*)(hn + (size_t)m * HDIM + j0 + jl), pk.u,
                           __ATOMIC_RELAXED, __HIP_MEMORY_SCOPE_AGENT);
      }
      if (t == SEQ - 1) hcat[(size_t)m * (2 * HDIM) + j0 + jl] = (f16)h;
    }

    // drain this wave's sc1 stores to the coherence point
    asm volatile("s_waitcnt vmcnt(0)" ::: "memory");
    __syncthreads();

    if (t < SEQ - 1) {
      // publish (plain sc1 store, no RMW), then x-phase of t+1 under the shadow
      if (tid == 0)
        __hip_atomic_store(mflag + wgj, (unsigned int)(t + 1),
                           __ATOMIC_RELAXED, __HIP_MEMORY_SCOPE_AGENT);
      XPHASE(t + 1)
      __builtin_amdgcn_sched_barrier(0);   // pin x-phase before the poll
    }
  }
#undef XPHASE
}

// ---------------- p = hcat @ Wp^T + bp via MFMA (f16 in, f32 out) ----------------
__global__ __launch_bounds__(256) void gemmp_k(const f16* __restrict__ A,
                                               const f16* __restrict__ B,
                                               const float* __restrict__ bias,
                                               float* __restrict__ out) {
  __shared__ __align__(16) f16 lsA[64 * 136];
  __shared__ __align__(16) f16 lsB[64 * 136];
  int tid = threadIdx.x;
  int m0 = blockIdx.x * 64, n0 = blockIdx.y * 64;
  int w = tid >> 6, lane = tid & 63;
  int wm = (w >> 1) * 32, wn = (w & 1) * 32;
  int l15 = lane & 15, l4 = lane >> 4;
  f32x4 acc[2][2] = {};
  for (int kt = 0; kt < 16; ++kt) {            // K = 2048
    int k0 = kt << 7;
    #pragma unroll
    for (int cc = 0; cc < 4; ++cc) {
      int idx = tid + cc * 256;
      int row = idx >> 4, c8 = (idx & 15) << 3;
      *(f16x8*)&lsA[row * 136 + c8] = *(const f16x8*)(A + (size_t)(m0 + row) * (2 * HDIM) + k0 + c8);
      *(f16x8*)&lsB[row * 136 + c8] = *(const f16x8*)(B + (size_t)(n0 + row) * (2 * HDIM) + k0 + c8);
    }
    __syncthreads();
    #pragma unroll
    for (int ks = 0; ks < 4; ++ks) {
      int ko = ks * 32 + l4 * 8;
      f16x8 a0 = *(const f16x8*)&lsA[(wm + l15) * 136 + ko];
      f16x8 a1 = *(const f16x8*)&lsA[(wm + 16 + l15) * 136 + ko];
      f16x8 b0 = *(const f16x8*)&lsB[(wn + l15) * 136 + ko];
      f16x8 b1 = *(const f16x8*)&lsB[(wn + 16 + l15) * 136 + ko];
      acc[0][0] = __builtin_amdgcn_mfma_f32_16x16x32_f16(a0, b0, acc[0][0], 0, 0, 0);
      acc[0][1] = __builtin_amdgcn_mfma_f32_16x16x32_f16(a0, b1, acc[0][1], 0, 0, 0);
      acc[1][0] = __builtin_amdgcn_mfma_f32_16x16x32_f16(a1, b0, acc[1][0], 0, 0, 0);
      acc[1][1] = __builtin_amdgcn_mfma_f32_16x16x32_f16(a1, b1, acc[1][1], 0, 0, 0);
    }
    __syncthreads();
  }
  #pragma unroll
  for (int mi = 0; mi < 2; ++mi)
    #pragma unroll
    for (int ni = 0; ni < 2; ++ni)
      #pragma unroll
      for (int r = 0; r < 4; ++r) {
        int m = m0 + wm + mi * 16 + l4 * 4 + r;
        int n = n0 + wn + ni * 16 + l15;
        out[(size_t)m * PDIM + n] = acc[mi][ni][r] + bias[n];
      }
}

// ---------------- out = sigmoid(p @ Wc^T + bc) ----------------
__global__ __launch_bounds__(64) void proj2_k(const float* __restrict__ p,
                                              const float* __restrict__ Wc,
                                              const float* __restrict__ bc,
                                              float* __restrict__ out) {
  int m = blockIdx.x, l = threadIdx.x;
  float pv[8];
  #pragma unroll
  for (int q = 0; q < 8; ++q) pv[q] = p[(size_t)m * PDIM + l + 64 * q];
  #pragma unroll
  for (int c = 0; c < ODIM; ++c) {
    float s = 0.f;
    #pragma unroll
    for (int q = 0; q < 8; ++q) s += pv[q] * Wc[c * PDIM + l + 64 * q];
    #pragma unroll
    for (int off = 32; off > 0; off >>= 1) s += __shfl_down(s, off);
    if (l == 0) out[m * ODIM + c] = 1.f / (1.f + __expf(-(s + bc[c])));
  }
}

extern "C" void kernel_launch(void* const* d_in, const int* in_sizes, int n_in,
                              void* d_out, int out_size, void* d_ws, size_t ws_size,
                              hipStream_t stream) {
  const int*   seq   = (const int*)d_in[0];
  const float* emb   = (const float*)d_in[1];
  const float* wih_f = (const float*)d_in[2];
  const float* whh_f = (const float*)d_in[3];
  const float* bih_f = (const float*)d_in[4];
  const float* bhh_f = (const float*)d_in[5];
  const float* wih_b = (const float*)d_in[6];
  const float* bih_b = (const float*)d_in[8];
  const float* bhh_b = (const float*)d_in[9];
  const float* Wp    = (const float*)d_in[10];
  const float* bp    = (const float*)d_in[11];
  const float* Wc    = (const float*)d_in[12];
  const float* bc    = (const float*)d_in[13];

  char* ws = (char*)d_ws;
  f16*   xs    = (f16*)(ws + XS_OFF);
  f16*   wrep  = (f16*)(ws + WREP_OFF);
  f16*   wb    = (f16*)(ws + WB_OFF);
  f16*   wpf   = (f16*)(ws + WPF_OFF);
  float* biasf = (float*)(ws + BIASF_OFF);
  float* biasb = (float*)(ws + BIASB_OFF);
  f16*   h0    = (f16*)(ws + H0_OFF);
  f16*   h1    = (f16*)(ws + H1_OFF);
  float* cb    = (float*)(ws + CB_OFF);
  unsigned int* flags = (unsigned int*)(ws + FLG_OFF);
  f16*   hcatf = (f16*)(ws + HCATF_OFF);
  float* p     = (float*)(ws + P_OFF);

  // zero h0, h1, cb, flags (contiguous)
  hipMemsetAsync(ws + H0_OFF, 0, (FLG_OFF + 1024) - H0_OFF, stream);

  wrep_k<<<(GDIM * KCAT / 8) / 256, 256, 0, stream>>>(wih_f, whh_f, wrep);
  wb_k<<<(GDIM * EDIM / 8) / 256, 256, 0, stream>>>(wih_b, wb);
  cvt8_k<<<(PDIM * 2 * HDIM / 8) / 256, 256, 0, stream>>>(Wp, wpf);
  bias_k<<<(2 * GDIM) / 256, 256, 0, stream>>>(bih_f, bhh_f, bih_b, bhh_b, biasf, biasb);
  embed_k<<<SEQ * BATCH, 64, 0, stream>>>(seq, emb, xs);

  // backward cell collapses to ONE step on xs[0] with zero state; h -> hcat cols [H, 2H)
  lstm_step<<<dim3(4, 64), 256, 0, stream>>>(xs, xs, EDIM, EDIM, EDIM,
      wb, EDIM, biasb, cb, cb, hcatf + HDIM, 2 * HDIM);

  // forward scan: one persistent cooperative kernel, 128 steps
  {
    void* kargs[] = { (void*)&xs, (void*)&wrep, (void*)&biasf, (void*)&h0,
                      (void*)&h1, (void*)&hcatf, (void*)&flags };
    hipLaunchCooperativeKernel((const void*)lstm_persist, dim3(256), dim3(512),
                               kargs, 0, stream);
  }

  gemmp_k<<<dim3(4, 8), 256, 0, stream>>>(hcatf, wpf, bp, p);
  proj2_k<<<BATCH, 64, 0, stream>>>(p, Wc, bc, (float*)d_out);
}

// Round 7
// 1441.933 us; speedup vs baseline: 3.1521x; 1.2844x over previous
//
#include <hip/hip_runtime.h>

#define BATCH 256
#define SEQ   128
#define EDIM  512
#define HDIM  1024
#define GDIM  4096   // 4*H
#define KCAT  1536   // E + H
#define PDIM  512
#define ODIM  6

typedef _Float16 f16;
typedef _Float16 f16x8 __attribute__((ext_vector_type(8)));
typedef float f32x4 __attribute__((ext_vector_type(4)));

// ---------------- workspace layout (bytes) ----------------
static const size_t XS_OFF    = 0;                                      // f16 [SEQ][BATCH][EDIM]
static const size_t WREP_OFF  = XS_OFF    + (size_t)SEQ*BATCH*EDIM*2;   // f16 repacked fwd W, 12.6 MB
static const size_t WB_OFF    = WREP_OFF  + (size_t)GDIM*KCAT*2;        // f16 [GDIM][EDIM]
static const size_t WPF_OFF   = WB_OFF    + (size_t)GDIM*EDIM*2;        // f16 [PDIM][2*HDIM]
static const size_t BIASF_OFF = WPF_OFF   + (size_t)PDIM*2*HDIM*2;      // f32 [GDIM]
static const size_t BIASB_OFF = BIASF_OFF + (size_t)GDIM*4;             // f32 [GDIM]
// ---- zeroed region start ----
static const size_t H0_OFF    = BIASB_OFF + (size_t)GDIM*4;             // f16 [BATCH][HDIM]
static const size_t H1_OFF    = H0_OFF    + (size_t)BATCH*HDIM*2;       // f16 [BATCH][HDIM]
static const size_t CB_OFF    = H1_OFF    + (size_t)BATCH*HDIM*2;       // f32 [BATCH][HDIM]
static const size_t FLG_OFF   = CB_OFF    + (size_t)BATCH*HDIM*4;       // u32 [4][64] flags
// ---- zeroed region end (FLG_OFF + 1024) ----
static const size_t HCATF_OFF = FLG_OFF   + 1024;                       // f16 [BATCH][2*HDIM]
static const size_t P_OFF     = HCATF_OFF + (size_t)BATCH*2*HDIM*2;     // f32 [BATCH][PDIM]

// ---------------- embedding gather + tanh -> f16 ----------------
__global__ __launch_bounds__(64) void embed_k(const int* __restrict__ seq,
                                              const float* __restrict__ emb,
                                              f16* __restrict__ xs) {
  int bid = blockIdx.x;                 // t*256 + b
  int t = bid >> 8, b = bid & 255;
  int tok = seq[b * SEQ + t];
  const float* src = emb + (size_t)tok * EDIM + threadIdx.x * 8;
  f16* dst = xs + (size_t)bid * EDIM + threadIdx.x * 8;
  float4 v0 = *(const float4*)src;
  float4 v1 = *(const float4*)(src + 4);
  f16x8 o;
  o[0] = (f16)tanhf(v0.x); o[1] = (f16)tanhf(v0.y);
  o[2] = (f16)tanhf(v0.z); o[3] = (f16)tanhf(v0.w);
  o[4] = (f16)tanhf(v1.x); o[5] = (f16)tanhf(v1.y);
  o[6] = (f16)tanhf(v1.z); o[7] = (f16)tanhf(v1.w);
  *(f16x8*)dst = o;
}

// ---------------- forward-W repack: per (j-tile, wave, iter, gate) 1KB frags --
// K-chunk map (must match lstm_persist): wave wv, iter i in [0,6):
//   i<2 : x chunk, k = 64*wv + 32*i
//   i>=2: h chunk, k = 512 + 64*wv + 32*((i-2)&1) + 512*((i-2)>>1)
// frag id = ((jt*8 + wv)*6 + i)*4 + g ; layout: frag[lane][8 f16]
__global__ __launch_bounds__(256) void wrep_k(const float* __restrict__ wih,
                                              const float* __restrict__ whh,
                                              f16* __restrict__ wrep) {
  int gid = blockIdx.x * 256 + threadIdx.x;      // 12288 frags * 64 lanes
  int lane = gid & 63;
  int fid = gid >> 6;
  int g = fid & 3;
  int i = (fid >> 2) % 6;
  int wv = (fid / 24) & 7;
  int jt = fid / 192;
  int l15 = lane & 15, l4 = lane >> 4;
  int row = (g << 10) + (jt << 4) + l15;
  int ck = (i < 2) ? (64 * wv + 32 * i)
                   : (512 + 64 * wv + 32 * ((i - 2) & 1) + 512 * ((i - 2) >> 1));
  int k = ck + l4 * 8;
  const float* src = (k < EDIM) ? (wih + (size_t)row * EDIM + k)
                                : (whh + (size_t)row * HDIM + (k - EDIM));
  float4 v0 = *(const float4*)src;
  float4 v1 = *(const float4*)(src + 4);
  f16x8 o;
  o[0] = (f16)v0.x; o[1] = (f16)v0.y; o[2] = (f16)v0.z; o[3] = (f16)v0.w;
  o[4] = (f16)v1.x; o[5] = (f16)v1.y; o[6] = (f16)v1.z; o[7] = (f16)v1.w;
  *(f16x8*)(wrep + (size_t)fid * 512 + lane * 8) = o;
}

__global__ __launch_bounds__(256) void wb_k(const float* __restrict__ wih,
                                            f16* __restrict__ wb) {
  int idx = blockIdx.x * 256 + threadIdx.x;    // EDIM/8 = 64 chunks per row
  int n = idx >> 6, c8 = (idx & 63) * 8;
  const float* src = wih + (size_t)n * EDIM + c8;
  float4 v0 = *(const float4*)src;
  float4 v1 = *(const float4*)(src + 4);
  f16x8 o;
  o[0] = (f16)v0.x; o[1] = (f16)v0.y; o[2] = (f16)v0.z; o[3] = (f16)v0.w;
  o[4] = (f16)v1.x; o[5] = (f16)v1.y; o[6] = (f16)v1.z; o[7] = (f16)v1.w;
  *(f16x8*)(wb + (size_t)n * EDIM + c8) = o;
}

// generic f32 -> f16, 8 elems/thread
__global__ __launch_bounds__(256) void cvt8_k(const float* __restrict__ src,
                                              f16* __restrict__ dst) {
  int idx = blockIdx.x * 256 + threadIdx.x;
  const float* s = src + (size_t)idx * 8;
  float4 v0 = *(const float4*)s;
  float4 v1 = *(const float4*)(s + 4);
  f16x8 o;
  o[0] = (f16)v0.x; o[1] = (f16)v0.y; o[2] = (f16)v0.z; o[3] = (f16)v0.w;
  o[4] = (f16)v1.x; o[5] = (f16)v1.y; o[6] = (f16)v1.z; o[7] = (f16)v1.w;
  *(f16x8*)(dst + (size_t)idx * 8) = o;
}

__global__ __launch_bounds__(256) void bias_k(const float* __restrict__ bih_f,
                                              const float* __restrict__ bhh_f,
                                              const float* __restrict__ bih_b,
                                              const float* __restrict__ bhh_b,
                                              float* __restrict__ biasf,
                                              float* __restrict__ biasb) {
  int i = blockIdx.x * 256 + threadIdx.x;
  if (i < GDIM) biasf[i] = bih_f[i] + bhh_f[i];
  else { int k = i - GDIM; biasb[k] = bih_b[k] + bhh_b[k]; }
}

// ---------------- one-shot LSTM step (backward cell, h0=c0=0) ----------------
__global__ __launch_bounds__(256) void lstm_step(
    const f16* __restrict__ A1, const f16* __restrict__ A2,
    int ld2, int K1, int Ktot,
    const f16* __restrict__ W, int ldw,
    const float* __restrict__ bias,
    const float* cin, float* cout,
    f16* __restrict__ hf16, int ldh)
{
  __shared__ __align__(16) f16 lsA[64 * 136];
  __shared__ __align__(16) f16 lsB[64 * 136];
  __shared__ float lsG[64 * 65];

  int tid = threadIdx.x;
  int m0 = blockIdx.x * 64;
  int j0 = blockIdx.y * 16;
  int w = tid >> 6, lane = tid & 63;
  int wm = (w >> 1) * 32, wn = (w & 1) * 32;
  int l15 = lane & 15, l4 = lane >> 4;

  f32x4 acc[2][2] = {};
  int nk = Ktot >> 7;

  for (int kt = 0; kt < nk; ++kt) {
    int k0 = kt << 7;
    #pragma unroll
    for (int cc = 0; cc < 4; ++cc) {
      int idx = tid + cc * 256;
      int row = idx >> 4, c8 = (idx & 15) << 3;
      int k = k0 + c8;
      const f16* sa = (k < K1) ? (A1 + (size_t)(m0 + row) * EDIM + k)
                               : (A2 + (size_t)(m0 + row) * ld2 + (k - K1));
      *(f16x8*)&lsA[row * 136 + c8] = *(const f16x8*)sa;
      int ng = ((row >> 4) << 10) + j0 + (row & 15);
      *(f16x8*)&lsB[row * 136 + c8] = *(const f16x8*)(W + (size_t)ng * ldw + k);
    }
    __syncthreads();
    #pragma unroll
    for (int ks = 0; ks < 4; ++ks) {
      int ko = ks * 32 + l4 * 8;
      f16x8 a0 = *(const f16x8*)&lsA[(wm + l15) * 136 + ko];
      f16x8 a1 = *(const f16x8*)&lsA[(wm + 16 + l15) * 136 + ko];
      f16x8 b0 = *(const f16x8*)&lsB[(wn + l15) * 136 + ko];
      f16x8 b1 = *(const f16x8*)&lsB[(wn + 16 + l15) * 136 + ko];
      acc[0][0] = __builtin_amdgcn_mfma_f32_16x16x32_f16(a0, b0, acc[0][0], 0, 0, 0);
      acc[0][1] = __builtin_amdgcn_mfma_f32_16x16x32_f16(a0, b1, acc[0][1], 0, 0, 0);
      acc[1][0] = __builtin_amdgcn_mfma_f32_16x16x32_f16(a1, b0, acc[1][0], 0, 0, 0);
      acc[1][1] = __builtin_amdgcn_mfma_f32_16x16x32_f16(a1, b1, acc[1][1], 0, 0, 0);
    }
    __syncthreads();
  }

  #pragma unroll
  for (int mi = 0; mi < 2; ++mi)
    #pragma unroll
    for (int ni = 0; ni < 2; ++ni) {
      int col = wn + ni * 16 + l15;
      int mr = wm + mi * 16 + l4 * 4;
      #pragma unroll
      for (int r = 0; r < 4; ++r)
        lsG[(mr + r) * 65 + col] = acc[mi][ni][r];
    }
  __syncthreads();

  int jl = tid & 15, mb = tid >> 4;
  int j = j0 + jl;
  #pragma unroll
  for (int mm = 0; mm < 4; ++mm) {
    int ml = mb + mm * 16;
    int m = m0 + ml;
    float gi = lsG[ml * 65 +      jl] + bias[j];
    float gf = lsG[ml * 65 + 16 + jl] + bias[HDIM + j];
    float gg = lsG[ml * 65 + 32 + jl] + bias[2 * HDIM + j];
    float go = lsG[ml * 65 + 48 + jl] + bias[3 * HDIM + j];
    float si = 1.f / (1.f + __expf(-gi));
    float sf = 1.f / (1.f + __expf(-gf));
    float so = 1.f / (1.f + __expf(-go));
    float c  = sf * cin[m * HDIM + j] + si * tanhf(gg);
    cout[m * HDIM + j] = c;
    float h = so * tanhf(c);
    hf16[(size_t)m * ldh + j] = (f16)h;
  }
}

// ---------------- persistent forward scan -------------------------------------
// 256 WGs cooperative x 512 threads. chain = wg>>6 (m0=chain*64), j0=(wg&63)*16.
// h exchange: producers store h via sc1 write-through + vmcnt drain + flag store;
// consumers poll flags (64 lanes, 1 RTT), then COLLECTIVELY stage the chain's
// full 64x1024 h slice into LDS with 16 independent plain coherent loads
// (global_load_dwordx4 sc0 sc1) per thread -> single-RTT exchange, no atomic/
// VGPR-pressure serialization. MFMA h A-frags then read from LDS. The LDS
// h-buffer aliases the reduce buffer (disjoint phases, barrier-separated).
__global__ __launch_bounds__(512) void lstm_persist(
    const f16* __restrict__ xs, const f16* __restrict__ wrep,
    const float* __restrict__ bias,
    f16* h0, f16* h1, f16* __restrict__ hcat,
    unsigned int* __restrict__ flags)
{
  union LdsU {
    float red[8][64][66];                // 135168 B reduce buffer
    f16   hb[64 * 1040];                 // 133120 B h stage, row stride 2080 B
  };
  __shared__ LdsU ls;
  __shared__ unsigned int sTok;
  int tid = threadIdx.x;
  int wg = blockIdx.x;
  int chain = wg >> 6;
  int m0 = chain << 6;
  int wgj = wg & 63;
  int j0 = wgj << 4;
  int wv = tid >> 6, lane = tid & 63;
  int l15 = lane & 15, l4 = lane >> 4;

  // per-thread W fragment base (contiguous 24 frags x 1KB per wave)
  const f16* wbase = wrep + ((size_t)(wgj * 8 + wv) * 24) * 512 + lane * 8;

  int kb = 64 * wv + l4 * 8;             // wave-base k offset (elements)
  size_t offX[4];
  #pragma unroll
  for (int ms = 0; ms < 4; ++ms)
    offX[ms] = (size_t)(m0 + ms * 16 + l15) * EDIM + kb;

  int jl = tid & 15, mb = tid >> 4;      // mb in [0,32)
  float creg[2] = {0.f, 0.f};
  float bg[4];
  #pragma unroll
  for (int g = 0; g < 4; ++g) bg[g] = bias[(g << 10) + j0 + jl];

  unsigned int* mflag = flags + chain * 64;   // 64 slots (256 B) per chain

  f32x4 acc[4][4];                       // [gate][m-sub]
  f16x8 xa[2][4];
  f16x8 wb0[4], wb1[4], wb2[4], wb3[4];

// x-phase: load x frags + first 3 W groups, run iters 0-1 (zero-init folded
// into iter0 via zero C operand). h-independent -> runs under barrier shadow.
#define XPHASE(TT)                                                             \
  {                                                                            \
    const f16* xtg = xs + (size_t)(TT) * BATCH * EDIM;                         \
    _Pragma("unroll") for (int g = 0; g < 4; ++g) {                            \
      wb0[g] = *(const f16x8*)(wbase + (size_t)(0 * 4 + g) * 512);             \
      wb1[g] = *(const f16x8*)(wbase + (size_t)(1 * 4 + g) * 512);             \
      wb2[g] = *(const f16x8*)(wbase + (size_t)(2 * 4 + g) * 512);             \
    }                                                                          \
    _Pragma("unroll") for (int d = 0; d < 2; ++d)                              \
      _Pragma("unroll") for (int ms = 0; ms < 4; ++ms)                         \
        xa[d][ms] = *(const f16x8*)(xtg + offX[ms] + 32 * d);                  \
    _Pragma("unroll") for (int g = 0; g < 4; ++g)                              \
      _Pragma("unroll") for (int ms = 0; ms < 4; ++ms)                         \
        acc[g][ms] = __builtin_amdgcn_mfma_f32_16x16x32_f16(                   \
            xa[0][ms], wb0[g], f32x4{0.f, 0.f, 0.f, 0.f}, 0, 0, 0);            \
    _Pragma("unroll") for (int g = 0; g < 4; ++g)                              \
      _Pragma("unroll") for (int ms = 0; ms < 4; ++ms)                         \
        acc[g][ms] = __builtin_amdgcn_mfma_f32_16x16x32_f16(                   \
            xa[1][ms], wb1[g], acc[g][ms], 0, 0, 0);                           \
  }

  XPHASE(0)

  // collective-stage addressing: thread covers global row m0+(tid>>3),
  // 16 B at (tid&7)*16 + c*128 within the 2048 B row (c = 0..15)
  int srow = tid >> 3, scol = (tid & 7) * 16;
  f16* lw = ls.hb + (size_t)srow * 1040 + (tid & 7) * 8;   // f16 units

  #pragma unroll 1
  for (int t = 0; t < SEQ; ++t) {
    // ---- wait for h(t-1): wave0 lanes read all 64 flags, one RTT ----
    size_t hg = 0;
    if (t > 0) {
      if (tid < 64) {
        unsigned int tgt = (unsigned int)t;
        unsigned int obs = 0, spins = 0;
        do {
          obs = __hip_atomic_load(mflag + tid, __ATOMIC_RELAXED, __HIP_MEMORY_SCOPE_AGENT);
          ++spins;
        } while (!__all((int)(obs >= tgt)) && spins < (1u << 18));  // watchdog
        if (tid == 0) sTok = obs;
      }
      __syncthreads();
      hg = (size_t)(sTok >> 31);         // always 0; data-dependency fence
    }
    const f16* hpg = ((t & 1) ? h1 : h0) + hg;
    f16* hn = (t & 1) ? h0 : h1;

    // ---- collective h stage: 16 independent coherent dwordx4 loads ----
    {
      const char* hbase = (const char*)(hpg + (size_t)(m0 + srow) * HDIM) + scol;
      float4 hv[16];
      asm volatile("global_load_dwordx4 %0, %1, off sc0 sc1"             : "=v"(hv[0])  : "v"(hbase) : "memory");
      asm volatile("global_load_dwordx4 %0, %1, off offset:128 sc0 sc1"  : "=v"(hv[1])  : "v"(hbase) : "memory");
      asm volatile("global_load_dwordx4 %0, %1, off offset:256 sc0 sc1"  : "=v"(hv[2])  : "v"(hbase) : "memory");
      asm volatile("global_load_dwordx4 %0, %1, off offset:384 sc0 sc1"  : "=v"(hv[3])  : "v"(hbase) : "memory");
      asm volatile("global_load_dwordx4 %0, %1, off offset:512 sc0 sc1"  : "=v"(hv[4])  : "v"(hbase) : "memory");
      asm volatile("global_load_dwordx4 %0, %1, off offset:640 sc0 sc1"  : "=v"(hv[5])  : "v"(hbase) : "memory");
      asm volatile("global_load_dwordx4 %0, %1, off offset:768 sc0 sc1"  : "=v"(hv[6])  : "v"(hbase) : "memory");
      asm volatile("global_load_dwordx4 %0, %1, off offset:896 sc0 sc1"  : "=v"(hv[7])  : "v"(hbase) : "memory");
      asm volatile("global_load_dwordx4 %0, %1, off offset:1024 sc0 sc1" : "=v"(hv[8])  : "v"(hbase) : "memory");
      asm volatile("global_load_dwordx4 %0, %1, off offset:1152 sc0 sc1" : "=v"(hv[9])  : "v"(hbase) : "memory");
      asm volatile("global_load_dwordx4 %0, %1, off offset:1280 sc0 sc1" : "=v"(hv[10]) : "v"(hbase) : "memory");
      asm volatile("global_load_dwordx4 %0, %1, off offset:1408 sc0 sc1" : "=v"(hv[11]) : "v"(hbase) : "memory");
      asm volatile("global_load_dwordx4 %0, %1, off offset:1536 sc0 sc1" : "=v"(hv[12]) : "v"(hbase) : "memory");
      asm volatile("global_load_dwordx4 %0, %1, off offset:1664 sc0 sc1" : "=v"(hv[13]) : "v"(hbase) : "memory");
      asm volatile("global_load_dwordx4 %0, %1, off offset:1792 sc0 sc1" : "=v"(hv[14]) : "v"(hbase) : "memory");
      asm volatile("global_load_dwordx4 %0, %1, off offset:1920 sc0 sc1" : "=v"(hv[15]) : "v"(hbase) : "memory");
      asm volatile("s_waitcnt vmcnt(0)" ::: "memory");
      __builtin_amdgcn_sched_barrier(0);   // nothing sinks above the drain
      #pragma unroll
      for (int c = 0; c < 16; ++c)
        *(float4*)(lw + c * 64) = hv[c];   // 128 B apart in LDS row
    }
    __syncthreads();

    // ---- h iters 2..5: A-frags from LDS, W dbuf from global ----
    #pragma unroll
    for (int ip = 0; ip < 4; ++ip) {
      f16x8 hf[4];
      int kh = 64 * wv + 32 * (ip & 1) + 512 * (ip >> 1);
      #pragma unroll
      for (int ms = 0; ms < 4; ++ms)
        hf[ms] = *(const f16x8*)(ls.hb + (size_t)(ms * 16 + l15) * 1040 + kh + l4 * 8);
      if (ip == 0)
        #pragma unroll
        for (int g = 0; g < 4; ++g)
          wb3[g] = *(const f16x8*)(wbase + (size_t)(3 * 4 + g) * 512);
      if (ip == 1)
        #pragma unroll
        for (int g = 0; g < 4; ++g)
          wb0[g] = *(const f16x8*)(wbase + (size_t)(4 * 4 + g) * 512);
      if (ip == 2)
        #pragma unroll
        for (int g = 0; g < 4; ++g)
          wb1[g] = *(const f16x8*)(wbase + (size_t)(5 * 4 + g) * 512);
      #pragma unroll
      for (int g = 0; g < 4; ++g) {
        f16x8 wcur = (ip == 0) ? wb2[g] : (ip == 1) ? wb3[g] : (ip == 2) ? wb0[g] : wb1[g];
        #pragma unroll
        for (int ms = 0; ms < 4; ++ms)
          acc[g][ms] = __builtin_amdgcn_mfma_f32_16x16x32_f16(hf[ms], wcur, acc[g][ms], 0, 0, 0);
      }
    }
    __syncthreads();                       // h reads done; ls.red may overwrite

    // ---- cross-wave K reduction (C/D: row = l4*4+r, col = l15) ----
    #pragma unroll
    for (int g = 0; g < 4; ++g)
      #pragma unroll
      for (int ms = 0; ms < 4; ++ms)
        #pragma unroll
        for (int r = 0; r < 4; ++r)
          ls.red[wv][ms * 16 + l4 * 4 + r][g * 16 + l15] = acc[g][ms][r];
    __syncthreads();

    // ---- pointwise: 512 threads x 2 rows each ----
    #pragma unroll
    for (int mm = 0; mm < 2; ++mm) {
      int ml = mb + (mm << 5);
      int m = m0 + ml;
      float ga[4];
      #pragma unroll
      for (int g = 0; g < 4; ++g) {
        float s = bg[g];
        #pragma unroll
        for (int u = 0; u < 8; ++u) s += ls.red[u][ml][g * 16 + jl];
        ga[g] = s;
      }
      float si = 1.f / (1.f + __expf(-ga[0]));
      float sf = 1.f / (1.f + __expf(-ga[1]));
      float so = 1.f / (1.f + __expf(-ga[3]));
      float c = sf * creg[mm] + si * tanhf(ga[2]);
      creg[mm] = c;
      float h = so * tanhf(c);
      float hx = __shfl_xor(h, 1);
      if ((jl & 1) == 0) {
        union { f16 h2[2]; unsigned int u; } pk;
        pk.h2[0] = (f16)h; pk.h2[1] = (f16)hx;
        __hip_atomic_store((unsigned int*)(hn + (size_t)m * HDIM + j0 + jl), pk.u,
                           __ATOMIC_RELAXED, __HIP_MEMORY_SCOPE_AGENT);
      }
      if (t == SEQ - 1) hcat[(size_t)m * (2 * HDIM) + j0 + jl] = (f16)h;
    }

    // drain this wave's sc1 stores to the coherence point
    asm volatile("s_waitcnt vmcnt(0)" ::: "memory");
    __syncthreads();

    if (t < SEQ - 1) {
      // publish (plain sc1 store, no RMW), then x-phase of t+1 under the shadow
      if (tid == 0)
        __hip_atomic_store(mflag + wgj, (unsigned int)(t + 1),
                           __ATOMIC_RELAXED, __HIP_MEMORY_SCOPE_AGENT);
      XPHASE(t + 1)
      __builtin_amdgcn_sched_barrier(0);   // pin x-phase before the poll
    }
  }
#undef XPHASE
}

// ---------------- p = hcat @ Wp^T + bp via MFMA (f16 in, f32 out) ----------------
__global__ __launch_bounds__(256) void gemmp_k(const f16* __restrict__ A,
                                               const f16* __restrict__ B,
                                               const float* __restrict__ bias,
                                               float* __restrict__ out) {
  __shared__ __align__(16) f16 lsA[64 * 136];
  __shared__ __align__(16) f16 lsB[64 * 136];
  int tid = threadIdx.x;
  int m0 = blockIdx.x * 64, n0 = blockIdx.y * 64;
  int w = tid >> 6, lane = tid & 63;
  int wm = (w >> 1) * 32, wn = (w & 1) * 32;
  int l15 = lane & 15, l4 = lane >> 4;
  f32x4 acc[2][2] = {};
  for (int kt = 0; kt < 16; ++kt) {            // K = 2048
    int k0 = kt << 7;
    #pragma unroll
    for (int cc = 0; cc < 4; ++cc) {
      int idx = tid + cc * 256;
      int row = idx >> 4, c8 = (idx & 15) << 3;
      *(f16x8*)&lsA[row * 136 + c8] = *(const f16x8*)(A + (size_t)(m0 + row) * (2 * HDIM) + k0 + c8);
      *(f16x8*)&lsB[row * 136 + c8] = *(const f16x8*)(B + (size_t)(n0 + row) * (2 * HDIM) + k0 + c8);
    }
    __syncthreads();
    #pragma unroll
    for (int ks = 0; ks < 4; ++ks) {
      int ko = ks * 32 + l4 * 8;
      f16x8 a0 = *(const f16x8*)&lsA[(wm + l15) * 136 + ko];
      f16x8 a1 = *(const f16x8*)&lsA[(wm + 16 + l15) * 136 + ko];
      f16x8 b0 = *(const f16x8*)&lsB[(wn + l15) * 136 + ko];
      f16x8 b1 = *(const f16x8*)&lsB[(wn + 16 + l15) * 136 + ko];
      acc[0][0] = __builtin_amdgcn_mfma_f32_16x16x32_f16(a0, b0, acc[0][0], 0, 0, 0);
      acc[0][1] = __builtin_amdgcn_mfma_f32_16x16x32_f16(a0, b1, acc[0][1], 0, 0, 0);
      acc[1][0] = __builtin_amdgcn_mfma_f32_16x16x32_f16(a1, b0, acc[1][0], 0, 0, 0);
      acc[1][1] = __builtin_amdgcn_mfma_f32_16x16x32_f16(a1, b1, acc[1][1], 0, 0, 0);
    }
    __syncthreads();
  }
  #pragma unroll
  for (int mi = 0; mi < 2; ++mi)
    #pragma unroll
    for (int ni = 0; ni < 2; ++ni)
      #pragma unroll
      for (int r = 0; r < 4; ++r) {
        int m = m0 + wm + mi * 16 + l4 * 4 + r;
        int n = n0 + wn + ni * 16 + l15;
        out[(size_t)m * PDIM + n] = acc[mi][ni][r] + bias[n];
      }
}

// ---------------- out = sigmoid(p @ Wc^T + bc) ----------------
__global__ __launch_bounds__(64) void proj2_k(const float* __restrict__ p,
                                              const float* __restrict__ Wc,
                                              const float* __restrict__ bc,
                                              float* __restrict__ out) {
  int m = blockIdx.x, l = threadIdx.x;
  float pv[8];
  #pragma unroll
  for (int q = 0; q < 8; ++q) pv[q] = p[(size_t)m * PDIM + l + 64 * q];
  #pragma unroll
  for (int c = 0; c < ODIM; ++c) {
    float s = 0.f;
    #pragma unroll
    for (int q = 0; q < 8; ++q) s += pv[q] * Wc[c * PDIM + l + 64 * q];
    #pragma unroll
    for (int off = 32; off > 0; off >>= 1) s += __shfl_down(s, off);
    if (l == 0) out[m * ODIM + c] = 1.f / (1.f + __expf(-(s + bc[c])));
  }
}

extern "C" void kernel_launch(void* const* d_in, const int* in_sizes, int n_in,
                              void* d_out, int out_size, void* d_ws, size_t ws_size,
                              hipStream_t stream) {
  const int*   seq   = (const int*)d_in[0];
  const float* emb   = (const float*)d_in[1];
  const float* wih_f = (const float*)d_in[2];
  const float* whh_f = (const float*)d_in[3];
  const float* bih_f = (const float*)d_in[4];
  const float* bhh_f = (const float*)d_in[5];
  const float* wih_b = (const float*)d_in[6];
  const float* bih_b = (const float*)d_in[8];
  const float* bhh_b = (const float*)d_in[9];
  const float* Wp    = (const float*)d_in[10];
  const float* bp    = (const float*)d_in[11];
  const float* Wc    = (const float*)d_in[12];
  const float* bc    = (const float*)d_in[13];

  char* ws = (char*)d_ws;
  f16*   xs    = (f16*)(ws + XS_OFF);
  f16*   wrep  = (f16*)(ws + WREP_OFF);
  f16*   wb    = (f16*)(ws + WB_OFF);
  f16*   wpf   = (f16*)(ws + WPF_OFF);
  float* biasf = (float*)(ws + BIASF_OFF);
  float* biasb = (float*)(ws + BIASB_OFF);
  f16*   h0    = (f16*)(ws + H0_OFF);
  f16*   h1    = (f16*)(ws + H1_OFF);
  float* cb    = (float*)(ws + CB_OFF);
  unsigned int* flags = (unsigned int*)(ws + FLG_OFF);
  f16*   hcatf = (f16*)(ws + HCATF_OFF);
  float* p     = (float*)(ws + P_OFF);

  // zero h0, h1, cb, flags (contiguous)
  hipMemsetAsync(ws + H0_OFF, 0, (FLG_OFF + 1024) - H0_OFF, stream);

  wrep_k<<<(GDIM * KCAT / 8) / 256, 256, 0, stream>>>(wih_f, whh_f, wrep);
  wb_k<<<(GDIM * EDIM / 8) / 256, 256, 0, stream>>>(wih_b, wb);
  cvt8_k<<<(PDIM * 2 * HDIM / 8) / 256, 256, 0, stream>>>(Wp, wpf);
  bias_k<<<(2 * GDIM) / 256, 256, 0, stream>>>(bih_f, bhh_f, bih_b, bhh_b, biasf, biasb);
  embed_k<<<SEQ * BATCH, 64, 0, stream>>>(seq, emb, xs);

  // backward cell collapses to ONE step on xs[0] with zero state; h -> hcat cols [H, 2H)
  lstm_step<<<dim3(4, 64), 256, 0, stream>>>(xs, xs, EDIM, EDIM, EDIM,
      wb, EDIM, biasb, cb, cb, hcatf + HDIM, 2 * HDIM);

  // forward scan: one persistent cooperative kernel, 128 steps
  {
    void* kargs[] = { (void*)&xs, (void*)&wrep, (void*)&biasf, (void*)&h0,
                      (void*)&h1, (void*)&hcatf, (void*)&flags };
    hipLaunchCooperativeKernel((const void*)lstm_persist, dim3(256), dim3(512),
                               kargs, 0, stream);
  }

  gemmp_k<<<dim3(4, 8), 256, 0, stream>>>(hcatf, wpf, bp, p);
  proj2_k<<<BATCH, 64, 0, stream>>>(p, Wc, bc, (float*)d_out);
}